// Round 1
// baseline (181.084 us; speedup 1.0000x reference)
//
#include <hip/hip_runtime.h>

#define NELEMS 10

// ase covalent radii (Cordero 2008), padded to 119
__constant__ float c_cov[119] = {
    0.2f, 0.31f, 0.28f, 1.28f, 0.96f, 0.84f, 0.76f, 0.71f, 0.66f, 0.57f, 0.58f, 1.66f,
    1.41f, 1.21f, 1.11f, 1.07f, 1.05f, 1.02f, 1.06f, 2.03f, 1.76f, 1.70f, 1.60f, 1.53f,
    1.39f, 1.39f, 1.32f, 1.26f, 1.24f, 1.32f, 1.22f, 1.22f, 1.20f, 1.19f, 1.20f, 1.20f,
    1.16f, 2.20f, 1.95f, 1.90f, 1.75f, 1.64f, 1.54f, 1.47f, 1.46f, 1.42f, 1.39f, 1.45f,
    1.44f, 1.42f, 1.39f, 1.39f, 1.38f, 1.39f, 1.40f, 2.44f, 2.15f, 2.07f, 2.04f, 2.03f,
    2.01f, 1.99f, 1.98f, 1.98f, 1.96f, 1.94f, 1.92f, 1.92f, 1.89f, 1.90f, 1.87f, 1.87f,
    1.75f, 1.70f, 1.62f, 1.51f, 1.44f, 1.41f, 1.36f, 1.36f, 1.32f, 1.45f, 1.46f, 1.48f,
    1.40f, 1.50f, 1.50f, 2.60f, 2.21f, 2.15f, 2.06f, 2.00f, 1.96f, 1.90f, 1.87f, 1.80f,
    1.69f,
    0.2f, 0.2f, 0.2f, 0.2f, 0.2f, 0.2f, 0.2f, 0.2f, 0.2f, 0.2f, 0.2f,
    0.2f, 0.2f, 0.2f, 0.2f, 0.2f, 0.2f, 0.2f, 0.2f, 0.2f, 0.2f, 0.2f
};

// Per-node precompute: argmax of one-hot -> element -> (Z, Z^0.3, cov_radius)
__global__ void zbl_node_prep(const float* __restrict__ node_attrs,
                              const int* __restrict__ atomic_numbers,
                              float4* __restrict__ tab, int n_nodes) {
    int n = blockIdx.x * blockDim.x + threadIdx.x;
    if (n >= n_nodes) return;
    const float* a = node_attrs + (size_t)n * NELEMS;
    int best = 0;
    float bv = a[0];
#pragma unroll
    for (int k = 1; k < NELEMS; ++k) {
        float v = a[k];
        if (v > bv) { bv = v; best = k; }
    }
    int Z = atomic_numbers[best];
    float zf = (float)Z;
    float z03 = powf(zf, 0.3f);
    float cov = c_cov[Z];
    tab[n] = make_float4(zf, z03, cov, 0.0f);
}

__global__ void zbl_edge(const float* __restrict__ x,
                         const int* __restrict__ edge_index,
                         const float4* __restrict__ tab,
                         float* __restrict__ out, int n_edges) {
    int e = blockIdx.x * blockDim.x + threadIdx.x;
    if (e >= n_edges) return;

    int s = edge_index[e];             // sender
    int r = edge_index[n_edges + e];   // receiver
    float xv = x[e];

    float4 tu = tab[s];
    float4 tv = tab[r];

    // a = 0.4543*0.529 / (Zu^0.3 + Zv^0.3);  r/a = x*(Zu^0.3+Zv^0.3)/0.2403247
    const float inv_a_pref = 1.0f / (0.4543f * 0.529f);
    float roa = xv * (tu.y + tv.y) * inv_a_pref;

    float phi = 0.1818f  * __expf(-3.2f    * roa)
              + 0.5099f  * __expf(-0.9423f * roa)
              + 0.2802f  * __expf(-0.4028f * roa)
              + 0.02817f * __expf(-0.2016f * roa);

    float v = 14.3996f * tu.x * tv.x / xv * phi;

    // polynomial envelope, p = 6
    float rmax = tu.z + tv.z;
    float rr = xv / rmax;
    float rr2 = rr * rr;
    float rr3 = rr2 * rr;
    float rr6 = rr3 * rr3;
    float rr7 = rr6 * rr;
    float rr8 = rr7 * rr;
    float env = 1.0f - 28.0f * rr6 + 48.0f * rr7 - 21.0f * rr8;
    env = (xv < rmax) ? env : 0.0f;

    float val = 0.5f * v * env;
#if defined(__HIP_PLATFORM_AMD__)
    unsafeAtomicAdd(out + r, val);
#else
    atomicAdd(out + r, val);
#endif
}

extern "C" void kernel_launch(void* const* d_in, const int* in_sizes, int n_in,
                              void* d_out, int out_size, void* d_ws, size_t ws_size,
                              hipStream_t stream) {
    const float* x              = (const float*)d_in[0];
    const float* node_attrs     = (const float*)d_in[1];
    const int*   edge_index     = (const int*)d_in[2];
    const int*   atomic_numbers = (const int*)d_in[3];
    float*       out            = (float*)d_out;

    int n_edges = in_sizes[0];            // x is [E,1]
    int n_nodes = in_sizes[1] / NELEMS;   // node_attrs is [N,10]

    float4* tab = (float4*)d_ws;          // 16 B * n_nodes = 1.6 MB scratch

    hipMemsetAsync(d_out, 0, (size_t)out_size * sizeof(float), stream);

    int bs = 256;
    int nb_nodes = (n_nodes + bs - 1) / bs;
    zbl_node_prep<<<nb_nodes, bs, 0, stream>>>(node_attrs, atomic_numbers, tab, n_nodes);

    int nb_edges = (n_edges + bs - 1) / bs;
    zbl_edge<<<nb_edges, bs, 0, stream>>>(x, edge_index, tab, out, n_edges);
}

// Round 2
// 142.747 us; speedup vs baseline: 1.2686x; 1.2686x over previous
//
#include <hip/hip_runtime.h>

#define NELEMS 10
#define W_SHIFT 7              // bucket width = 128 nodes
#define W 128
#define MAXNB 1024             // max buckets supported by static LDS arrays
#define NBLK 512               // blocks in hist/scatter passes
#define BS_HS 512              // threads per block in hist/scatter

// ase covalent radii (Cordero 2008), padded to 119
__constant__ float c_cov[119] = {
    0.2f, 0.31f, 0.28f, 1.28f, 0.96f, 0.84f, 0.76f, 0.71f, 0.66f, 0.57f, 0.58f, 1.66f,
    1.41f, 1.21f, 1.11f, 1.07f, 1.05f, 1.02f, 1.06f, 2.03f, 1.76f, 1.70f, 1.60f, 1.53f,
    1.39f, 1.39f, 1.32f, 1.26f, 1.24f, 1.32f, 1.22f, 1.22f, 1.20f, 1.19f, 1.20f, 1.20f,
    1.16f, 2.20f, 1.95f, 1.90f, 1.75f, 1.64f, 1.54f, 1.47f, 1.46f, 1.42f, 1.39f, 1.45f,
    1.44f, 1.42f, 1.39f, 1.39f, 1.38f, 1.39f, 1.40f, 2.44f, 2.15f, 2.07f, 2.04f, 2.03f,
    2.01f, 1.99f, 1.98f, 1.98f, 1.96f, 1.94f, 1.92f, 1.92f, 1.89f, 1.90f, 1.87f, 1.87f,
    1.75f, 1.70f, 1.62f, 1.51f, 1.44f, 1.41f, 1.36f, 1.36f, 1.32f, 1.45f, 1.46f, 1.48f,
    1.40f, 1.50f, 1.50f, 2.60f, 2.21f, 2.15f, 2.06f, 2.00f, 1.96f, 1.90f, 1.87f, 1.80f,
    1.69f,
    0.2f, 0.2f, 0.2f, 0.2f, 0.2f, 0.2f, 0.2f, 0.2f, 0.2f, 0.2f, 0.2f,
    0.2f, 0.2f, 0.2f, 0.2f, 0.2f, 0.2f, 0.2f, 0.2f, 0.2f, 0.2f, 0.2f
};

// Per-node precompute: argmax of one-hot -> element -> (Z, Z^0.3, cov_radius)
__global__ void zbl_node_prep(const float* __restrict__ node_attrs,
                              const int* __restrict__ atomic_numbers,
                              float4* __restrict__ tab, int n_nodes) {
    int n = blockIdx.x * blockDim.x + threadIdx.x;
    if (n >= n_nodes) return;
    const float* a = node_attrs + (size_t)n * NELEMS;
    int best = 0;
    float bv = a[0];
#pragma unroll
    for (int k = 1; k < NELEMS; ++k) {
        float v = a[k];
        if (v > bv) { bv = v; best = k; }
    }
    int Z = atomic_numbers[best];
    float zf = (float)Z;
    float z03 = powf(zf, 0.3f);
    float cov = c_cov[Z];
    tab[n] = make_float4(zf, z03, cov, 0.0f);
}

__device__ __forceinline__ float zbl_edge_value(float xv, float4 tu, float4 tv) {
    const float inv_a_pref = 1.0f / (0.4543f * 0.529f);
    float roa = xv * (tu.y + tv.y) * inv_a_pref;
    float phi = 0.1818f  * __expf(-3.2f    * roa)
              + 0.5099f  * __expf(-0.9423f * roa)
              + 0.2802f  * __expf(-0.4028f * roa)
              + 0.02817f * __expf(-0.2016f * roa);
    float v = 14.3996f * tu.x * tv.x / xv * phi;
    float rmax = tu.z + tv.z;
    float rr = xv / rmax;
    float rr2 = rr * rr;
    float rr3 = rr2 * rr;
    float rr6 = rr3 * rr3;
    float rr7 = rr6 * rr;
    float rr8 = rr7 * rr;
    float env = 1.0f - 28.0f * rr6 + 48.0f * rr7 - 21.0f * rr8;
    env = (xv < rmax) ? env : 0.0f;
    return 0.5f * v * env;
}

// ---------------- Pass 1: per-block bucket histogram (LDS, no global atomics)
__global__ void zbl_hist(const int* __restrict__ recv, int n_edges, int chunk,
                         int nb, int* __restrict__ blockHist /*[b*NBLK+blk]*/) {
    __shared__ int h[MAXNB];
    for (int i = threadIdx.x; i < nb; i += blockDim.x) h[i] = 0;
    __syncthreads();
    int blk = blockIdx.x;
    int e0 = blk * chunk;
    int e1 = min(n_edges, e0 + chunk);
    for (int e = e0 + threadIdx.x; e < e1; e += blockDim.x)
        atomicAdd(&h[recv[e] >> W_SHIFT], 1);
    __syncthreads();
    for (int i = threadIdx.x; i < nb; i += blockDim.x)
        blockHist[i * NBLK + blk] = h[i];
}

// ---------------- Pass 2a: per-bucket exclusive scan across blocks
// grid = nb blocks, blockDim = NBLK
__global__ void zbl_scan_blocks(const int* __restrict__ blockHist, int nb,
                                int* __restrict__ offT /*[blk*nb+b]*/,
                                int* __restrict__ totals) {
    __shared__ int s[NBLK];
    int b = blockIdx.x;
    int t = threadIdx.x;
    int v = blockHist[b * NBLK + t];
    s[t] = v;
    __syncthreads();
    for (int d = 1; d < NBLK; d <<= 1) {
        int add = (t >= d) ? s[t - d] : 0;
        __syncthreads();
        s[t] += add;
        __syncthreads();
    }
    offT[t * nb + b] = s[t] - v;          // exclusive within bucket
    if (t == NBLK - 1) totals[b] = s[t];  // bucket total
}

// ---------------- Pass 2b: exclusive scan of bucket totals -> base[nb+1]
// grid = 1 block, blockDim = MAXNB
__global__ void zbl_scan_buckets(const int* __restrict__ totals, int nb,
                                 int* __restrict__ base) {
    __shared__ int s[MAXNB];
    int t = threadIdx.x;
    int v = (t < nb) ? totals[t] : 0;
    s[t] = v;
    __syncthreads();
    for (int d = 1; d < MAXNB; d <<= 1) {
        int add = (t >= d) ? s[t - d] : 0;
        __syncthreads();
        s[t] += add;
        __syncthreads();
    }
    if (t < nb) base[t] = s[t] - v;
    if (t == nb - 1) base[nb] = s[t];
}

// ---------------- Pass 3: compute edge values + scatter into bucket-sorted slots
__global__ void zbl_scatter(const float* __restrict__ x,
                            const int* __restrict__ ei,
                            const float4* __restrict__ tab,
                            int n_edges, int chunk, int nb,
                            const int* __restrict__ base,
                            const int* __restrict__ offT,
                            float* __restrict__ val,
                            unsigned char* __restrict__ lr) {
    __shared__ int cur[MAXNB];
    int blk = blockIdx.x;
    for (int i = threadIdx.x; i < nb; i += blockDim.x)
        cur[i] = base[i] + offT[blk * nb + i];
    __syncthreads();
    int e0 = blk * chunk;
    int e1 = min(n_edges, e0 + chunk);
    for (int e = e0 + threadIdx.x; e < e1; e += blockDim.x) {
        int s = ei[e];
        int r = ei[n_edges + e];
        float xv = x[e];
        float4 tu = tab[s];
        float4 tv = tab[r];
        float v = zbl_edge_value(xv, tu, tv);
        int b = r >> W_SHIFT;
        int pos = atomicAdd(&cur[b], 1);   // LDS atomic only
        val[pos] = v;
        lr[pos] = (unsigned char)(r & (W - 1));
    }
}

// ---------------- Pass 4: per-bucket LDS reduction, one coalesced write
// grid = nb blocks, blockDim = 256
__global__ void zbl_reduce(const float* __restrict__ val,
                           const unsigned char* __restrict__ lr,
                           const int* __restrict__ base,
                           int n_nodes, float* __restrict__ out) {
    __shared__ float acc[W];
    int b = blockIdx.x;
    int t = threadIdx.x;
    if (t < W) acc[t] = 0.0f;
    __syncthreads();
    int p0 = base[b], p1 = base[b + 1];
    for (int p = p0 + t; p < p1; p += blockDim.x)
        atomicAdd(&acc[lr[p]], val[p]);
    __syncthreads();
    int node = b * W + t;
    if (t < W && node < n_nodes) out[node] = acc[t];
}

// ---------------- Fallback: direct global-atomic path (R1 kernel)
__global__ void zbl_edge_atomic(const float* __restrict__ x,
                                const int* __restrict__ edge_index,
                                const float4* __restrict__ tab,
                                float* __restrict__ out, int n_edges) {
    int e = blockIdx.x * blockDim.x + threadIdx.x;
    if (e >= n_edges) return;
    int s = edge_index[e];
    int r = edge_index[n_edges + e];
    float xv = x[e];
    float4 tu = tab[s];
    float4 tv = tab[r];
    float v = zbl_edge_value(xv, tu, tv);
#if defined(__HIP_PLATFORM_AMD__)
    unsafeAtomicAdd(out + r, v);
#else
    atomicAdd(out + r, v);
#endif
}

extern "C" void kernel_launch(void* const* d_in, const int* in_sizes, int n_in,
                              void* d_out, int out_size, void* d_ws, size_t ws_size,
                              hipStream_t stream) {
    const float* x              = (const float*)d_in[0];
    const float* node_attrs     = (const float*)d_in[1];
    const int*   edge_index     = (const int*)d_in[2];
    const int*   atomic_numbers = (const int*)d_in[3];
    float*       out            = (float*)d_out;

    int n_edges = in_sizes[0];            // x is [E,1]
    int n_nodes = in_sizes[1] / NELEMS;   // node_attrs is [N,10]
    int nb = (n_nodes + W - 1) / W;       // buckets of 128 nodes

    // workspace layout (256B-aligned slabs)
    size_t off = 0;
    auto alloc = [&](size_t bytes) {
        size_t o = off;
        off = (off + bytes + 255) & ~(size_t)255;
        return o;
    };
    char* ws = (char*)d_ws;
    size_t tab_o    = alloc((size_t)n_nodes * sizeof(float4));
    size_t bhist_o  = alloc((size_t)nb * NBLK * sizeof(int));
    size_t offT_o   = alloc((size_t)NBLK * nb * sizeof(int));
    size_t totals_o = alloc((size_t)nb * sizeof(int));
    size_t base_o   = alloc((size_t)(nb + 1) * sizeof(int));
    size_t val_o    = alloc((size_t)n_edges * sizeof(float));
    size_t lr_o     = alloc((size_t)n_edges * sizeof(unsigned char));
    size_t need = off;

    float4* tab = (float4*)(ws + tab_o);

    int bs = 256;
    int nb_nodes = (n_nodes + bs - 1) / bs;
    zbl_node_prep<<<nb_nodes, bs, 0, stream>>>(node_attrs, atomic_numbers, tab, n_nodes);

    if (nb <= MAXNB && need <= ws_size) {
        int* blockHist = (int*)(ws + bhist_o);
        int* offT      = (int*)(ws + offT_o);
        int* totals    = (int*)(ws + totals_o);
        int* base      = (int*)(ws + base_o);
        float* val     = (float*)(ws + val_o);
        unsigned char* lr = (unsigned char*)(ws + lr_o);

        int chunk = (n_edges + NBLK - 1) / NBLK;
        const int* recv = edge_index + n_edges;

        zbl_hist<<<NBLK, BS_HS, 0, stream>>>(recv, n_edges, chunk, nb, blockHist);
        zbl_scan_blocks<<<nb, NBLK, 0, stream>>>(blockHist, nb, offT, totals);
        zbl_scan_buckets<<<1, MAXNB, 0, stream>>>(totals, nb, base);
        zbl_scatter<<<NBLK, BS_HS, 0, stream>>>(x, edge_index, tab, n_edges, chunk,
                                                nb, base, offT, val, lr);
        zbl_reduce<<<nb, 256, 0, stream>>>(val, lr, base, n_nodes, out);
    } else {
        // fallback: direct global-atomic path
        hipMemsetAsync(d_out, 0, (size_t)out_size * sizeof(float), stream);
        int nb_edges = (n_edges + bs - 1) / bs;
        zbl_edge_atomic<<<nb_edges, bs, 0, stream>>>(x, edge_index, tab, out, n_edges);
    }
}

// Round 3
// 127.397 us; speedup vs baseline: 1.4214x; 1.1205x over previous
//
#include <hip/hip_runtime.h>

#define NELEMS 10
#define W_SHIFT 10             // bucket width = 1024 nodes
#define W 1024
#define MAXNB 1024             // max buckets supported by static LDS arrays
#define NBLK 1024              // blocks in hist/scatter passes
#define BS_HS 256              // threads per block in hist/scatter

// ase covalent radii (Cordero 2008), padded to 119
__constant__ float c_cov[119] = {
    0.2f, 0.31f, 0.28f, 1.28f, 0.96f, 0.84f, 0.76f, 0.71f, 0.66f, 0.57f, 0.58f, 1.66f,
    1.41f, 1.21f, 1.11f, 1.07f, 1.05f, 1.02f, 1.06f, 2.03f, 1.76f, 1.70f, 1.60f, 1.53f,
    1.39f, 1.39f, 1.32f, 1.26f, 1.24f, 1.32f, 1.22f, 1.22f, 1.20f, 1.19f, 1.20f, 1.20f,
    1.16f, 2.20f, 1.95f, 1.90f, 1.75f, 1.64f, 1.54f, 1.47f, 1.46f, 1.42f, 1.39f, 1.45f,
    1.44f, 1.42f, 1.39f, 1.39f, 1.38f, 1.39f, 1.40f, 2.44f, 2.15f, 2.07f, 2.04f, 2.03f,
    2.01f, 1.99f, 1.98f, 1.98f, 1.96f, 1.94f, 1.92f, 1.92f, 1.89f, 1.90f, 1.87f, 1.87f,
    1.75f, 1.70f, 1.62f, 1.51f, 1.44f, 1.41f, 1.36f, 1.36f, 1.32f, 1.45f, 1.46f, 1.48f,
    1.40f, 1.50f, 1.50f, 2.60f, 2.21f, 2.15f, 2.06f, 2.00f, 1.96f, 1.90f, 1.87f, 1.80f,
    1.69f,
    0.2f, 0.2f, 0.2f, 0.2f, 0.2f, 0.2f, 0.2f, 0.2f, 0.2f, 0.2f, 0.2f,
    0.2f, 0.2f, 0.2f, 0.2f, 0.2f, 0.2f, 0.2f, 0.2f, 0.2f, 0.2f, 0.2f
};

// Per-node precompute: argmax of one-hot -> element -> (Z, Z^0.3, cov_radius)
__global__ void zbl_node_prep(const float* __restrict__ node_attrs,
                              const int* __restrict__ atomic_numbers,
                              float4* __restrict__ tab, int n_nodes) {
    int n = blockIdx.x * blockDim.x + threadIdx.x;
    if (n >= n_nodes) return;
    const float* a = node_attrs + (size_t)n * NELEMS;
    int best = 0;
    float bv = a[0];
#pragma unroll
    for (int k = 1; k < NELEMS; ++k) {
        float v = a[k];
        if (v > bv) { bv = v; best = k; }
    }
    int Z = atomic_numbers[best];
    float zf = (float)Z;
    float z03 = powf(zf, 0.3f);
    float cov = c_cov[Z];
    tab[n] = make_float4(zf, z03, cov, 0.0f);
}

__device__ __forceinline__ float zbl_edge_value(float xv, float4 tu, float4 tv) {
    const float inv_a_pref = 1.0f / (0.4543f * 0.529f);
    float roa = xv * (tu.y + tv.y) * inv_a_pref;
    float phi = 0.1818f  * __expf(-3.2f    * roa)
              + 0.5099f  * __expf(-0.9423f * roa)
              + 0.2802f  * __expf(-0.4028f * roa)
              + 0.02817f * __expf(-0.2016f * roa);
    float v = 14.3996f * tu.x * tv.x / xv * phi;
    float rmax = tu.z + tv.z;
    float rr = xv / rmax;
    float rr2 = rr * rr;
    float rr3 = rr2 * rr;
    float rr6 = rr3 * rr3;
    float rr7 = rr6 * rr;
    float rr8 = rr7 * rr;
    float env = 1.0f - 28.0f * rr6 + 48.0f * rr7 - 21.0f * rr8;
    env = (xv < rmax) ? env : 0.0f;
    return 0.5f * v * env;
}

// ---------------- Pass 1: per-block bucket histogram (LDS, no global atomics)
__global__ void zbl_hist(const int* __restrict__ recv, int n_edges, int chunk,
                         int nb, int* __restrict__ blockHist /*[b*NBLK+blk]*/) {
    __shared__ int h[MAXNB];
    for (int i = threadIdx.x; i < nb; i += blockDim.x) h[i] = 0;
    __syncthreads();
    int blk = blockIdx.x;
    int e0 = blk * chunk;
    int e1 = min(n_edges, e0 + chunk);
    for (int e = e0 + threadIdx.x; e < e1; e += blockDim.x)
        atomicAdd(&h[recv[e] >> W_SHIFT], 1);
    __syncthreads();
    for (int i = threadIdx.x; i < nb; i += blockDim.x)
        blockHist[i * NBLK + blk] = h[i];
}

// ---------------- Pass 2a: per-bucket exclusive scan across blocks
// grid = nb blocks, blockDim = NBLK
__global__ void zbl_scan_blocks(const int* __restrict__ blockHist, int nb,
                                int* __restrict__ offT /*[blk*nb+b]*/,
                                int* __restrict__ totals) {
    __shared__ int s[NBLK];
    int b = blockIdx.x;
    int t = threadIdx.x;
    int v = blockHist[b * NBLK + t];
    s[t] = v;
    __syncthreads();
    for (int d = 1; d < NBLK; d <<= 1) {
        int add = (t >= d) ? s[t - d] : 0;
        __syncthreads();
        s[t] += add;
        __syncthreads();
    }
    offT[t * nb + b] = s[t] - v;          // exclusive within bucket
    if (t == NBLK - 1) totals[b] = s[t];  // bucket total
}

// ---------------- Pass 2b: exclusive scan of bucket totals -> base[nb+1]
// grid = 1 block, blockDim = MAXNB
__global__ void zbl_scan_buckets(const int* __restrict__ totals, int nb,
                                 int* __restrict__ base) {
    __shared__ int s[MAXNB];
    int t = threadIdx.x;
    int v = (t < nb) ? totals[t] : 0;
    s[t] = v;
    __syncthreads();
    for (int d = 1; d < MAXNB; d <<= 1) {
        int add = (t >= d) ? s[t - d] : 0;
        __syncthreads();
        s[t] += add;
        __syncthreads();
    }
    if (t < nb) base[t] = s[t] - v;
    if (t == nb - 1) base[nb] = s[t];
}

// ---------------- Pass 3: compute edge values + scatter into bucket-sorted slots
__global__ void zbl_scatter(const float* __restrict__ x,
                            const int* __restrict__ ei,
                            const float4* __restrict__ tab,
                            int n_edges, int chunk, int nb,
                            const int* __restrict__ base,
                            const int* __restrict__ offT,
                            float* __restrict__ val,
                            unsigned short* __restrict__ lr) {
    __shared__ int cur[MAXNB];
    int blk = blockIdx.x;
    for (int i = threadIdx.x; i < nb; i += blockDim.x)
        cur[i] = base[i] + offT[blk * nb + i];
    __syncthreads();
    int e0 = blk * chunk;
    int e1 = min(n_edges, e0 + chunk);
    for (int e = e0 + threadIdx.x; e < e1; e += blockDim.x) {
        int s = ei[e];
        int r = ei[n_edges + e];
        float xv = x[e];
        float4 tu = tab[s];
        float4 tv = tab[r];
        float v = zbl_edge_value(xv, tu, tv);
        int b = r >> W_SHIFT;
        int pos = atomicAdd(&cur[b], 1);   // LDS atomic only
        val[pos] = v;
        lr[pos] = (unsigned short)(r & (W - 1));
    }
}

// ---------------- Pass 4: per-bucket LDS reduction, one coalesced write
// grid = nb blocks, blockDim = W (1024)
__global__ void zbl_reduce(const float* __restrict__ val,
                           const unsigned short* __restrict__ lr,
                           const int* __restrict__ base,
                           int n_nodes, float* __restrict__ out) {
    __shared__ float acc[W];
    int b = blockIdx.x;
    int t = threadIdx.x;
    acc[t] = 0.0f;
    __syncthreads();
    int p0 = base[b], p1 = base[b + 1];
    for (int p = p0 + t; p < p1; p += blockDim.x)
        atomicAdd(&acc[lr[p]], val[p]);
    __syncthreads();
    int node = b * W + t;
    if (node < n_nodes) out[node] = acc[t];
}

// ---------------- Fallback: direct global-atomic path (R1 kernel)
__global__ void zbl_edge_atomic(const float* __restrict__ x,
                                const int* __restrict__ edge_index,
                                const float4* __restrict__ tab,
                                float* __restrict__ out, int n_edges) {
    int e = blockIdx.x * blockDim.x + threadIdx.x;
    if (e >= n_edges) return;
    int s = edge_index[e];
    int r = edge_index[n_edges + e];
    float xv = x[e];
    float4 tu = tab[s];
    float4 tv = tab[r];
    float v = zbl_edge_value(xv, tu, tv);
#if defined(__HIP_PLATFORM_AMD__)
    unsafeAtomicAdd(out + r, v);
#else
    atomicAdd(out + r, v);
#endif
}

extern "C" void kernel_launch(void* const* d_in, const int* in_sizes, int n_in,
                              void* d_out, int out_size, void* d_ws, size_t ws_size,
                              hipStream_t stream) {
    const float* x              = (const float*)d_in[0];
    const float* node_attrs     = (const float*)d_in[1];
    const int*   edge_index     = (const int*)d_in[2];
    const int*   atomic_numbers = (const int*)d_in[3];
    float*       out            = (float*)d_out;

    int n_edges = in_sizes[0];            // x is [E,1]
    int n_nodes = in_sizes[1] / NELEMS;   // node_attrs is [N,10]
    int nb = (n_nodes + W - 1) / W;       // buckets of 1024 nodes

    // workspace layout (256B-aligned slabs)
    size_t off = 0;
    auto alloc = [&](size_t bytes) {
        size_t o = off;
        off = (off + bytes + 255) & ~(size_t)255;
        return o;
    };
    char* ws = (char*)d_ws;
    size_t tab_o    = alloc((size_t)n_nodes * sizeof(float4));
    size_t bhist_o  = alloc((size_t)nb * NBLK * sizeof(int));
    size_t offT_o   = alloc((size_t)NBLK * nb * sizeof(int));
    size_t totals_o = alloc((size_t)nb * sizeof(int));
    size_t base_o   = alloc((size_t)(nb + 1) * sizeof(int));
    size_t val_o    = alloc((size_t)n_edges * sizeof(float));
    size_t lr_o     = alloc((size_t)n_edges * sizeof(unsigned short));
    size_t need = off;

    float4* tab = (float4*)(ws + tab_o);

    int bs = 256;
    int nb_nodes = (n_nodes + bs - 1) / bs;
    zbl_node_prep<<<nb_nodes, bs, 0, stream>>>(node_attrs, atomic_numbers, tab, n_nodes);

    if (nb <= MAXNB && need <= ws_size) {
        int* blockHist = (int*)(ws + bhist_o);
        int* offT      = (int*)(ws + offT_o);
        int* totals    = (int*)(ws + totals_o);
        int* base      = (int*)(ws + base_o);
        float* val     = (float*)(ws + val_o);
        unsigned short* lr = (unsigned short*)(ws + lr_o);

        int chunk = (n_edges + NBLK - 1) / NBLK;
        const int* recv = edge_index + n_edges;

        zbl_hist<<<NBLK, BS_HS, 0, stream>>>(recv, n_edges, chunk, nb, blockHist);
        zbl_scan_blocks<<<nb, NBLK, 0, stream>>>(blockHist, nb, offT, totals);
        zbl_scan_buckets<<<1, MAXNB, 0, stream>>>(totals, nb, base);
        zbl_scatter<<<NBLK, BS_HS, 0, stream>>>(x, edge_index, tab, n_edges, chunk,
                                                nb, base, offT, val, lr);
        zbl_reduce<<<nb, W, 0, stream>>>(val, lr, base, n_nodes, out);
    } else {
        // fallback: direct global-atomic path
        hipMemsetAsync(d_out, 0, (size_t)out_size * sizeof(float), stream);
        int nb_edges = (n_edges + bs - 1) / bs;
        zbl_edge_atomic<<<nb_edges, bs, 0, stream>>>(x, edge_index, tab, out, n_edges);
    }
}

// Round 4
// 111.619 us; speedup vs baseline: 1.6223x; 1.1414x over previous
//
#include <hip/hip_runtime.h>

#define NELEMS 10
#define W_SHIFT 10             // bucket width = 1024 nodes
#define W 1024
#define MAXNB 1024             // scan_buckets capacity
#define MAXBL 128              // max buckets for sorted-scatter LDS arrays
#define CHUNKCAP 6400          // edges per block in hist/scatter
#define PADCAP 8448            // CHUNKCAP + MAXBL*16 headroom
#define BS_HS 512
#define MAXBLK 512             // max blocks supported by scan_blocks

// ase covalent radii (Cordero 2008), padded to 119
__constant__ float c_cov[119] = {
    0.2f, 0.31f, 0.28f, 1.28f, 0.96f, 0.84f, 0.76f, 0.71f, 0.66f, 0.57f, 0.58f, 1.66f,
    1.41f, 1.21f, 1.11f, 1.07f, 1.05f, 1.02f, 1.06f, 2.03f, 1.76f, 1.70f, 1.60f, 1.53f,
    1.39f, 1.39f, 1.32f, 1.26f, 1.24f, 1.32f, 1.22f, 1.22f, 1.20f, 1.19f, 1.20f, 1.20f,
    1.16f, 2.20f, 1.95f, 1.90f, 1.75f, 1.64f, 1.54f, 1.47f, 1.46f, 1.42f, 1.39f, 1.45f,
    1.44f, 1.42f, 1.39f, 1.39f, 1.38f, 1.39f, 1.40f, 2.44f, 2.15f, 2.07f, 2.04f, 2.03f,
    2.01f, 1.99f, 1.98f, 1.98f, 1.96f, 1.94f, 1.92f, 1.92f, 1.89f, 1.90f, 1.87f, 1.87f,
    1.75f, 1.70f, 1.62f, 1.51f, 1.44f, 1.41f, 1.36f, 1.36f, 1.32f, 1.45f, 1.46f, 1.48f,
    1.40f, 1.50f, 1.50f, 2.60f, 2.21f, 2.15f, 2.06f, 2.00f, 1.96f, 1.90f, 1.87f, 1.80f,
    1.69f,
    0.2f, 0.2f, 0.2f, 0.2f, 0.2f, 0.2f, 0.2f, 0.2f, 0.2f, 0.2f, 0.2f,
    0.2f, 0.2f, 0.2f, 0.2f, 0.2f, 0.2f, 0.2f, 0.2f, 0.2f, 0.2f, 0.2f
};

// Per-node precompute: argmax of one-hot -> element -> (Z, Z^0.3, cov_radius)
__global__ void zbl_node_prep(const float* __restrict__ node_attrs,
                              const int* __restrict__ atomic_numbers,
                              float4* __restrict__ tab, int n_nodes) {
    int n = blockIdx.x * blockDim.x + threadIdx.x;
    if (n >= n_nodes) return;
    const float* a = node_attrs + (size_t)n * NELEMS;
    int best = 0;
    float bv = a[0];
#pragma unroll
    for (int k = 1; k < NELEMS; ++k) {
        float v = a[k];
        if (v > bv) { bv = v; best = k; }
    }
    int Z = atomic_numbers[best];
    float zf = (float)Z;
    float z03 = powf(zf, 0.3f);
    float cov = c_cov[Z];
    tab[n] = make_float4(zf, z03, cov, 0.0f);
}

__device__ __forceinline__ float zbl_edge_value(float xv, float4 tu, float4 tv) {
    const float inv_a_pref = 1.0f / (0.4543f * 0.529f);
    float roa = xv * (tu.y + tv.y) * inv_a_pref;
    float phi = 0.1818f  * __expf(-3.2f    * roa)
              + 0.5099f  * __expf(-0.9423f * roa)
              + 0.2802f  * __expf(-0.4028f * roa)
              + 0.02817f * __expf(-0.2016f * roa);
    float v = 14.3996f * tu.x * tv.x / xv * phi;
    float rmax = tu.z + tv.z;
    float rr = xv / rmax;
    float rr2 = rr * rr;
    float rr3 = rr2 * rr;
    float rr6 = rr3 * rr3;
    float rr7 = rr6 * rr;
    float rr8 = rr7 * rr;
    float env = 1.0f - 28.0f * rr6 + 48.0f * rr7 - 21.0f * rr8;
    env = (xv < rmax) ? env : 0.0f;
    return 0.5f * v * env;
}

// ---------------- Pass 1: per-block bucket histogram (padded counts)
__global__ void zbl_hist(const int* __restrict__ recv, int n_edges, int chunk,
                         int nb, int nblk, int pad_m1,
                         int* __restrict__ blockHist /*[b*nblk+blk]*/) {
    __shared__ int h[MAXBL];
    for (int i = threadIdx.x; i < nb; i += blockDim.x) h[i] = 0;
    __syncthreads();
    int blk = blockIdx.x;
    int e0 = blk * chunk;
    int e1 = min(n_edges, e0 + chunk);
    for (int e = e0 + threadIdx.x; e < e1; e += blockDim.x)
        atomicAdd(&h[recv[e] >> W_SHIFT], 1);
    __syncthreads();
    for (int i = threadIdx.x; i < nb; i += blockDim.x)
        blockHist[i * nblk + blk] = (h[i] + pad_m1) & ~pad_m1;
}

// ---------------- Pass 2a: per-bucket exclusive scan across blocks
// grid = nb blocks, blockDim = MAXBLK
__global__ void zbl_scan_blocks(const int* __restrict__ blockHist, int nb, int nblk,
                                int* __restrict__ offT /*[blk*nb+b]*/,
                                int* __restrict__ totals) {
    __shared__ int s[MAXBLK];
    int b = blockIdx.x;
    int t = threadIdx.x;
    int v = (t < nblk) ? blockHist[b * nblk + t] : 0;
    s[t] = v;
    __syncthreads();
    for (int d = 1; d < MAXBLK; d <<= 1) {
        int add = (t >= d) ? s[t - d] : 0;
        __syncthreads();
        s[t] += add;
        __syncthreads();
    }
    if (t < nblk) offT[t * nb + b] = s[t] - v;     // exclusive within bucket
    if (t == MAXBLK - 1) totals[b] = s[t];         // bucket total (padded)
}

// ---------------- Pass 2b: exclusive scan of bucket totals -> base[nb+1]
// grid = 1 block, blockDim = MAXNB
__global__ void zbl_scan_buckets(const int* __restrict__ totals, int nb,
                                 int* __restrict__ base) {
    __shared__ int s[MAXNB];
    int t = threadIdx.x;
    int v = (t < nb) ? totals[t] : 0;
    s[t] = v;
    __syncthreads();
    for (int d = 1; d < MAXNB; d <<= 1) {
        int add = (t >= d) ? s[t - d] : 0;
        __syncthreads();
        s[t] += add;
        __syncthreads();
    }
    if (t < nb) base[t] = s[t] - v;
    if (t == nb - 1) base[nb] = s[t];
}

// ---------------- Pass 3: block-local counting sort in LDS, then coalesced
// full-line streaming writes. Pad entries have val=0 (inert in reduce).
__global__ __launch_bounds__(BS_HS)
void zbl_scatter_sorted(const float* __restrict__ x,
                        const int* __restrict__ ei,
                        const float4* __restrict__ tab,
                        int n_edges, int chunk, int nb, int pad_m1,
                        const int* __restrict__ base,
                        const int* __restrict__ offT,
                        float* __restrict__ val,
                        unsigned short* __restrict__ lr) {
    __shared__ float          val_s[PADCAP];
    __shared__ unsigned short lr_s[PADCAP];
    __shared__ unsigned char  b_s[PADCAP];
    __shared__ int cnt[MAXBL];
    __shared__ int scanbuf[MAXBL];
    __shared__ int lds_off[MAXBL + 1];
    __shared__ int cursor[MAXBL];
    __shared__ int delta[MAXBL];

    int blk = blockIdx.x;
    int t = threadIdx.x;
    int e0 = blk * chunk;
    int e1 = min(n_edges, e0 + chunk);
    const int* recv = ei + n_edges;

    for (int i = t; i < nb; i += blockDim.x) cnt[i] = 0;
    __syncthreads();
    for (int e = e0 + t; e < e1; e += blockDim.x)
        atomicAdd(&cnt[recv[e] >> W_SHIFT], 1);
    __syncthreads();

    // scan padded counts (Hillis-Steele over MAXBL slots)
    if (t < MAXBL) scanbuf[t] = (t < nb) ? ((cnt[t] + pad_m1) & ~pad_m1) : 0;
    __syncthreads();
    for (int d = 1; d < MAXBL; d <<= 1) {
        int add = 0;
        if (t < MAXBL && t >= d) add = scanbuf[t - d];
        __syncthreads();
        if (t < MAXBL) scanbuf[t] += add;
        __syncthreads();
    }
    if (t < MAXBL) lds_off[t + 1] = scanbuf[t];
    if (t == 0) lds_off[0] = 0;
    __syncthreads();

    if (t < nb) {
        cursor[t] = lds_off[t];
        delta[t]  = base[t] + offT[blk * nb + t] - lds_off[t];
    }
    int total = lds_off[nb];
    __syncthreads();

    // init staging (pad slots must be val=0, lr=0) and bucket-id map
    for (int p = t; p < total; p += blockDim.x) { val_s[p] = 0.0f; lr_s[p] = 0; }
    for (int b = t; b < nb; b += blockDim.x) {
        int s0 = lds_off[b], s1 = lds_off[b + 1];
        for (int p = s0; p < s1; ++p) b_s[p] = (unsigned char)b;
    }
    __syncthreads();

    // place edges into LDS staging (LDS cursor atomics only)
    for (int e = e0 + t; e < e1; e += blockDim.x) {
        int s = ei[e];
        int r = recv[e];
        float xv = x[e];
        float4 tu = tab[s];
        float4 tv = tab[r];
        float v = zbl_edge_value(xv, tu, tv);
        int b = r >> W_SHIFT;
        int pos = atomicAdd(&cursor[b], 1);
        val_s[pos] = v;
        lr_s[pos] = (unsigned short)(r & (W - 1));
    }
    __syncthreads();

    // streaming write-out: gdst = delta[bucket] + p, aligned since
    // base/offT/lds_off are all multiples of pad
    for (int p = t; p < total; p += blockDim.x) {
        int g = delta[b_s[p]] + p;
        val[g] = val_s[p];
        lr[g]  = lr_s[p];
    }
}

// ---------------- Pass 4: per-bucket LDS reduction, one coalesced write
// grid = nb blocks, blockDim = W (1024)
__global__ void zbl_reduce(const float* __restrict__ val,
                           const unsigned short* __restrict__ lr,
                           const int* __restrict__ base,
                           int n_nodes, float* __restrict__ out) {
    __shared__ float acc[W];
    int b = blockIdx.x;
    int t = threadIdx.x;
    acc[t] = 0.0f;
    __syncthreads();
    int p0 = base[b], p1 = base[b + 1];
    for (int p = p0 + t; p < p1; p += blockDim.x)
        atomicAdd(&acc[lr[p]], val[p]);
    __syncthreads();
    int node = b * W + t;
    if (node < n_nodes) out[node] = acc[t];
}

// ---------------- Fallback: direct global-atomic path
__global__ void zbl_edge_atomic(const float* __restrict__ x,
                                const int* __restrict__ edge_index,
                                const float4* __restrict__ tab,
                                float* __restrict__ out, int n_edges) {
    int e = blockIdx.x * blockDim.x + threadIdx.x;
    if (e >= n_edges) return;
    int s = edge_index[e];
    int r = edge_index[n_edges + e];
    float xv = x[e];
    float4 tu = tab[s];
    float4 tv = tab[r];
    float v = zbl_edge_value(xv, tu, tv);
#if defined(__HIP_PLATFORM_AMD__)
    unsafeAtomicAdd(out + r, v);
#else
    atomicAdd(out + r, v);
#endif
}

extern "C" void kernel_launch(void* const* d_in, const int* in_sizes, int n_in,
                              void* d_out, int out_size, void* d_ws, size_t ws_size,
                              hipStream_t stream) {
    const float* x              = (const float*)d_in[0];
    const float* node_attrs     = (const float*)d_in[1];
    const int*   edge_index     = (const int*)d_in[2];
    const int*   atomic_numbers = (const int*)d_in[3];
    float*       out            = (float*)d_out;

    int n_edges = in_sizes[0];            // x is [E,1]
    int n_nodes = in_sizes[1] / NELEMS;   // node_attrs is [N,10]
    int nb = (n_nodes + W - 1) / W;       // buckets of 1024 nodes
    int chunk = CHUNKCAP;
    int nblk = (n_edges + chunk - 1) / chunk;

    char* ws = (char*)d_ws;

    // choose the largest pad granularity whose workspace fits
    int pad = 0;
    size_t tab_o = 0, bhist_o = 0, offT_o = 0, totals_o = 0, base_o = 0,
           val_o = 0, lr_o = 0;
    for (int try_pad = 16; try_pad >= 1; try_pad >>= 1) {
        size_t off = 0;
        auto alloc = [&](size_t bytes) {
            size_t o = off;
            off = (off + bytes + 255) & ~(size_t)255;
            return o;
        };
        size_t cap = (size_t)n_edges + (size_t)nblk * nb * try_pad;
        tab_o    = alloc((size_t)n_nodes * sizeof(float4));
        bhist_o  = alloc((size_t)nb * nblk * sizeof(int));
        offT_o   = alloc((size_t)nblk * nb * sizeof(int));
        totals_o = alloc((size_t)nb * sizeof(int));
        base_o   = alloc((size_t)(nb + 1) * sizeof(int));
        val_o    = alloc(cap * sizeof(float));
        lr_o     = alloc(cap * sizeof(unsigned short));
        bool fits_lds = (chunk + nb * (try_pad - 1)) <= PADCAP;
        if (off <= ws_size && fits_lds) { pad = try_pad; break; }
    }

    float4* tab = (float4*)(ws + tab_o);
    int bs = 256;
    int nb_nodes = (n_nodes + bs - 1) / bs;
    zbl_node_prep<<<nb_nodes, bs, 0, stream>>>(node_attrs, atomic_numbers, tab, n_nodes);

    bool sorted_ok = (pad >= 1) && (nb <= MAXBL) && (nblk <= MAXBLK);

    if (sorted_ok) {
        int* blockHist = (int*)(ws + bhist_o);
        int* offT      = (int*)(ws + offT_o);
        int* totals    = (int*)(ws + totals_o);
        int* base      = (int*)(ws + base_o);
        float* val     = (float*)(ws + val_o);
        unsigned short* lr = (unsigned short*)(ws + lr_o);
        int pad_m1 = pad - 1;

        const int* recv = edge_index + n_edges;

        zbl_hist<<<nblk, BS_HS, 0, stream>>>(recv, n_edges, chunk, nb, nblk,
                                             pad_m1, blockHist);
        zbl_scan_blocks<<<nb, MAXBLK, 0, stream>>>(blockHist, nb, nblk, offT, totals);
        zbl_scan_buckets<<<1, MAXNB, 0, stream>>>(totals, nb, base);
        zbl_scatter_sorted<<<nblk, BS_HS, 0, stream>>>(x, edge_index, tab, n_edges,
                                                       chunk, nb, pad_m1, base, offT,
                                                       val, lr);
        zbl_reduce<<<nb, W, 0, stream>>>(val, lr, base, n_nodes, out);
    } else {
        // fallback: direct global-atomic path
        hipMemsetAsync(d_out, 0, (size_t)out_size * sizeof(float), stream);
        int nb_edges = (n_edges + bs - 1) / bs;
        zbl_edge_atomic<<<nb_edges, bs, 0, stream>>>(x, edge_index, tab, out, n_edges);
    }
}

// Round 5
// 98.242 us; speedup vs baseline: 1.8432x; 1.1362x over previous
//
#include <hip/hip_runtime.h>

#define NELEMS 10
#define W_SHIFT 10             // bucket width = 1024 nodes
#define W 1024
#define MAXNB 1024             // scan_buckets capacity
#define MAXBL 128              // max buckets for scatter LDS arrays
#define NBCAP 104              // PADCAP assumes nb <= 104
#define CHUNK 4096             // edges per block in hist/scatter
#define PAD 16                 // segment padding granularity (64B lines)
#define PADCAP (CHUNK + NBCAP * PAD)   // 5760
#define NGROUP (PADCAP / 16)           // 360
#define BS_HS 512
#define MAXBLK 1024            // max blocks supported by scan_blocks

// ase covalent radii (Cordero 2008), padded to 119
__constant__ float c_cov[119] = {
    0.2f, 0.31f, 0.28f, 1.28f, 0.96f, 0.84f, 0.76f, 0.71f, 0.66f, 0.57f, 0.58f, 1.66f,
    1.41f, 1.21f, 1.11f, 1.07f, 1.05f, 1.02f, 1.06f, 2.03f, 1.76f, 1.70f, 1.60f, 1.53f,
    1.39f, 1.39f, 1.32f, 1.26f, 1.24f, 1.32f, 1.22f, 1.22f, 1.20f, 1.19f, 1.20f, 1.20f,
    1.16f, 2.20f, 1.95f, 1.90f, 1.75f, 1.64f, 1.54f, 1.47f, 1.46f, 1.42f, 1.39f, 1.45f,
    1.44f, 1.42f, 1.39f, 1.39f, 1.38f, 1.39f, 1.40f, 2.44f, 2.15f, 2.07f, 2.04f, 2.03f,
    2.01f, 1.99f, 1.98f, 1.98f, 1.96f, 1.94f, 1.92f, 1.92f, 1.89f, 1.90f, 1.87f, 1.87f,
    1.75f, 1.70f, 1.62f, 1.51f, 1.44f, 1.41f, 1.36f, 1.36f, 1.32f, 1.45f, 1.46f, 1.48f,
    1.40f, 1.50f, 1.50f, 2.60f, 2.21f, 2.15f, 2.06f, 2.00f, 1.96f, 1.90f, 1.87f, 1.80f,
    1.69f,
    0.2f, 0.2f, 0.2f, 0.2f, 0.2f, 0.2f, 0.2f, 0.2f, 0.2f, 0.2f, 0.2f,
    0.2f, 0.2f, 0.2f, 0.2f, 0.2f, 0.2f, 0.2f, 0.2f, 0.2f, 0.2f, 0.2f
};

// Per-node precompute: argmax of one-hot -> element -> (Z, Z^0.3, cov_radius)
__global__ void zbl_node_prep(const float* __restrict__ node_attrs,
                              const int* __restrict__ atomic_numbers,
                              float4* __restrict__ tab, int n_nodes) {
    int n = blockIdx.x * blockDim.x + threadIdx.x;
    if (n >= n_nodes) return;
    const float* a = node_attrs + (size_t)n * NELEMS;
    int best = 0;
    float bv = a[0];
#pragma unroll
    for (int k = 1; k < NELEMS; ++k) {
        float v = a[k];
        if (v > bv) { bv = v; best = k; }
    }
    int Z = atomic_numbers[best];
    float zf = (float)Z;
    float z03 = powf(zf, 0.3f);
    float cov = c_cov[Z];
    tab[n] = make_float4(zf, z03, cov, 0.0f);
}

__device__ __forceinline__ float zbl_edge_value(float xv, float4 tu, float4 tv) {
    const float inv_a_pref = 1.0f / (0.4543f * 0.529f);
    float roa = xv * (tu.y + tv.y) * inv_a_pref;
    float phi = 0.1818f  * __expf(-3.2f    * roa)
              + 0.5099f  * __expf(-0.9423f * roa)
              + 0.2802f  * __expf(-0.4028f * roa)
              + 0.02817f * __expf(-0.2016f * roa);
    float v = 14.3996f * tu.x * tv.x / xv * phi;
    float rmax = tu.z + tv.z;
    float rr = xv / rmax;
    float rr2 = rr * rr;
    float rr3 = rr2 * rr;
    float rr6 = rr3 * rr3;
    float rr7 = rr6 * rr;
    float rr8 = rr7 * rr;
    float env = 1.0f - 28.0f * rr6 + 48.0f * rr7 - 21.0f * rr8;
    env = (xv < rmax) ? env : 0.0f;
    return 0.5f * v * env;
}

// ---------------- Pass 1: per-block bucket histogram (padded to PAD)
__global__ void zbl_hist(const int* __restrict__ recv, int n_edges,
                         int nb, int nblk,
                         int* __restrict__ blockHist /*[b*nblk+blk]*/) {
    __shared__ int h[MAXBL];
    for (int i = threadIdx.x; i < nb; i += blockDim.x) h[i] = 0;
    __syncthreads();
    int blk = blockIdx.x;
    int e0 = blk * CHUNK;
    int e1 = min(n_edges, e0 + CHUNK);
    for (int e = e0 + threadIdx.x; e < e1; e += blockDim.x)
        atomicAdd(&h[recv[e] >> W_SHIFT], 1);
    __syncthreads();
    for (int i = threadIdx.x; i < nb; i += blockDim.x)
        blockHist[i * nblk + blk] = (h[i] + (PAD - 1)) & ~(PAD - 1);
}

// ---------------- Pass 2a: per-bucket exclusive scan across blocks
// grid = nb blocks, blockDim = MAXBLK
__global__ void zbl_scan_blocks(const int* __restrict__ blockHist, int nb, int nblk,
                                int* __restrict__ offT /*[blk*nb+b]*/,
                                int* __restrict__ totals) {
    __shared__ int s[MAXBLK];
    int b = blockIdx.x;
    int t = threadIdx.x;
    int v = (t < nblk) ? blockHist[b * nblk + t] : 0;
    s[t] = v;
    __syncthreads();
    for (int d = 1; d < MAXBLK; d <<= 1) {
        int add = (t >= d) ? s[t - d] : 0;
        __syncthreads();
        s[t] += add;
        __syncthreads();
    }
    if (t < nblk) offT[t * nb + b] = s[t] - v;     // exclusive within bucket
    if (t == MAXBLK - 1) totals[b] = s[t];         // bucket total (padded)
}

// ---------------- Pass 2b: exclusive scan of bucket totals -> base[nb+1]
// grid = 1 block, blockDim = MAXNB
__global__ void zbl_scan_buckets(const int* __restrict__ totals, int nb,
                                 int* __restrict__ base) {
    __shared__ int s[MAXNB];
    int t = threadIdx.x;
    int v = (t < nb) ? totals[t] : 0;
    s[t] = v;
    __syncthreads();
    for (int d = 1; d < MAXNB; d <<= 1) {
        int add = (t >= d) ? s[t - d] : 0;
        __syncthreads();
        s[t] += add;
        __syncthreads();
    }
    if (t < nb) base[t] = s[t] - v;
    if (t == nb - 1) base[nb] = s[t];
}

// ---------------- Pass 3: block-local counting sort in LDS, full-line writes.
// Pad entries have val=0 (inert in reduce). Segments 16-aligned -> all 16
// entries of each group share one bucket -> tiny grp[] table, no b_s.
__global__ __launch_bounds__(BS_HS)
void zbl_scatter_sorted(const float* __restrict__ x,
                        const int* __restrict__ ei,
                        const float4* __restrict__ tab,
                        int n_edges, int nb,
                        const int* __restrict__ base,
                        const int* __restrict__ offT,
                        float* __restrict__ val,
                        unsigned short* __restrict__ lr) {
    __shared__ float          val_s[PADCAP];
    __shared__ unsigned short lr_s[PADCAP];
    __shared__ int scanv[MAXBL];
    __shared__ int lds_off[MAXBL + 1];
    __shared__ int cursor[MAXBL];
    __shared__ int delta[MAXBL];
    __shared__ unsigned char grp[NGROUP];

    int blk = blockIdx.x;
    int t = threadIdx.x;
    int e0 = blk * CHUNK;
    int e1 = min(n_edges, e0 + CHUNK);
    const int* recv = ei + n_edges;

    // count (reuse cursor as the histogram)
    for (int i = t; i < nb; i += BS_HS) cursor[i] = 0;
    __syncthreads();
    for (int e = e0 + t; e < e1; e += BS_HS)
        atomicAdd(&cursor[recv[e] >> W_SHIFT], 1);
    __syncthreads();

    // padded exclusive scan (Hillis-Steele over MAXBL slots)
    if (t < MAXBL) scanv[t] = (t < nb) ? ((cursor[t] + (PAD - 1)) & ~(PAD - 1)) : 0;
    __syncthreads();
    for (int d = 1; d < MAXBL; d <<= 1) {
        int add = 0;
        if (t < MAXBL && t >= d) add = scanv[t - d];
        __syncthreads();
        if (t < MAXBL) scanv[t] += add;
        __syncthreads();
    }
    if (t < MAXBL) lds_off[t + 1] = scanv[t];
    if (t == 0) lds_off[0] = 0;
    __syncthreads();

    int total = lds_off[nb];
    if (t < nb) {
        cursor[t] = lds_off[t];
        delta[t]  = base[t] + offT[blk * nb + t] - lds_off[t];
        int g0 = lds_off[t] >> 4, g1 = lds_off[t + 1] >> 4;
        for (int g = g0; g < g1; ++g) grp[g] = (unsigned char)t;
    }
    __syncthreads();

    // zero staging (pad slots must be val=0, lr in-range)
    for (int p = t; p < total; p += BS_HS) { val_s[p] = 0.0f; lr_s[p] = 0; }
    __syncthreads();

    // place edges (LDS cursor atomics only)
    for (int e = e0 + t; e < e1; e += BS_HS) {
        int s = ei[e];
        int r = recv[e];
        float xv = x[e];
        float4 tu = tab[s];
        float4 tv = tab[r];
        float v = zbl_edge_value(xv, tu, tv);
        int b = r >> W_SHIFT;
        int pos = atomicAdd(&cursor[b], 1);
        val_s[pos] = v;
        lr_s[pos] = (unsigned short)(r & (W - 1));
    }
    __syncthreads();

    // streaming write-out; delta[b] is a multiple of 16 -> g == p (mod 16)
    for (int p = t; p < total; p += BS_HS) {
        int g = delta[grp[p >> 4]] + p;
        val[g] = val_s[p];
        lr[g]  = lr_s[p];
    }
}

// ---------------- Pass 4: per-(bucket, slice) LDS reduction -> partials
// grid = (nb, kred), blockDim = 512
__global__ __launch_bounds__(512)
void zbl_reduce_partial(const float* __restrict__ val,
                        const unsigned short* __restrict__ lr,
                        const int* __restrict__ base,
                        int kred, float* __restrict__ partial) {
    __shared__ float acc[W];
    int b = blockIdx.x;
    int j = blockIdx.y;
    int t = threadIdx.x;
    acc[t] = 0.0f;
    acc[t + 512] = 0.0f;
    __syncthreads();
    int p0 = base[b], p1 = base[b + 1];
    int cnt = p1 - p0;
    int slice = ((cnt + kred - 1) / kred + 15) & ~15;
    int s0 = p0 + j * slice;
    int s1 = min(p1, s0 + slice);
    for (int p = s0 + t; p < s1; p += 512)
        atomicAdd(&acc[lr[p] & (W - 1)], val[p]);
    __syncthreads();
    float* dst = partial + (((size_t)b * kred + j) << W_SHIFT);
    dst[t] = acc[t];
    dst[t + 512] = acc[t + 512];
}

// ---------------- Pass 5: sum kred partials per node -> out
__global__ void zbl_combine(const float* __restrict__ partial, int kred,
                            int n_nodes, float* __restrict__ out) {
    int n = blockIdx.x * blockDim.x + threadIdx.x;
    if (n >= n_nodes) return;
    int b = n >> W_SHIFT;
    int t = n & (W - 1);
    float s = 0.0f;
    for (int j = 0; j < kred; ++j)
        s += partial[(((size_t)b * kred + j) << W_SHIFT) + t];
    out[n] = s;
}

// ---------------- Fallback: direct global-atomic path
__global__ void zbl_edge_atomic(const float* __restrict__ x,
                                const int* __restrict__ edge_index,
                                const float4* __restrict__ tab,
                                float* __restrict__ out, int n_edges) {
    int e = blockIdx.x * blockDim.x + threadIdx.x;
    if (e >= n_edges) return;
    int s = edge_index[e];
    int r = edge_index[n_edges + e];
    float xv = x[e];
    float4 tu = tab[s];
    float4 tv = tab[r];
    float v = zbl_edge_value(xv, tu, tv);
#if defined(__HIP_PLATFORM_AMD__)
    unsafeAtomicAdd(out + r, v);
#else
    atomicAdd(out + r, v);
#endif
}

extern "C" void kernel_launch(void* const* d_in, const int* in_sizes, int n_in,
                              void* d_out, int out_size, void* d_ws, size_t ws_size,
                              hipStream_t stream) {
    const float* x              = (const float*)d_in[0];
    const float* node_attrs     = (const float*)d_in[1];
    const int*   edge_index     = (const int*)d_in[2];
    const int*   atomic_numbers = (const int*)d_in[3];
    float*       out            = (float*)d_out;

    int n_edges = in_sizes[0];            // x is [E,1]
    int n_nodes = in_sizes[1] / NELEMS;   // node_attrs is [N,10]
    int nb = (n_nodes + W - 1) / W;       // buckets of 1024 nodes
    int nblk = (n_edges + CHUNK - 1) / CHUNK;

    char* ws = (char*)d_ws;

    // workspace layout; choose largest kred whose partial buffer fits
    int kred = 0;
    size_t tab_o = 0, bhist_o = 0, offT_o = 0, totals_o = 0, base_o = 0,
           val_o = 0, lr_o = 0, part_o = 0;
    for (int try_k = 8; try_k >= 1; try_k >>= 1) {
        size_t off = 0;
        auto alloc = [&](size_t bytes) {
            size_t o = off;
            off = (off + bytes + 255) & ~(size_t)255;
            return o;
        };
        size_t cap = (size_t)n_edges + (size_t)nblk * nb * (PAD - 1);
        tab_o    = alloc((size_t)n_nodes * sizeof(float4));
        bhist_o  = alloc((size_t)nb * nblk * sizeof(int));
        offT_o   = alloc((size_t)nblk * nb * sizeof(int));
        totals_o = alloc((size_t)nb * sizeof(int));
        base_o   = alloc((size_t)(nb + 1) * sizeof(int));
        val_o    = alloc(cap * sizeof(float));
        lr_o     = alloc(cap * sizeof(unsigned short));
        part_o   = alloc((size_t)nb * try_k * W * sizeof(float));
        if (off <= ws_size) { kred = try_k; break; }
    }

    float4* tab = (float4*)(ws + tab_o);
    int bs = 256;
    int nb_nodes = (n_nodes + bs - 1) / bs;
    zbl_node_prep<<<nb_nodes, bs, 0, stream>>>(node_attrs, atomic_numbers, tab, n_nodes);

    bool sorted_ok = (kred >= 1) && (nb <= NBCAP) && (nblk <= MAXBLK);

    if (sorted_ok) {
        int* blockHist = (int*)(ws + bhist_o);
        int* offT      = (int*)(ws + offT_o);
        int* totals    = (int*)(ws + totals_o);
        int* base      = (int*)(ws + base_o);
        float* val     = (float*)(ws + val_o);
        unsigned short* lr = (unsigned short*)(ws + lr_o);
        float* partial = (float*)(ws + part_o);

        const int* recv = edge_index + n_edges;

        zbl_hist<<<nblk, BS_HS, 0, stream>>>(recv, n_edges, nb, nblk, blockHist);
        zbl_scan_blocks<<<nb, MAXBLK, 0, stream>>>(blockHist, nb, nblk, offT, totals);
        zbl_scan_buckets<<<1, MAXNB, 0, stream>>>(totals, nb, base);
        zbl_scatter_sorted<<<nblk, BS_HS, 0, stream>>>(x, edge_index, tab, n_edges,
                                                       nb, base, offT, val, lr);
        zbl_reduce_partial<<<dim3(nb, kred), 512, 0, stream>>>(val, lr, base,
                                                               kred, partial);
        zbl_combine<<<(n_nodes + bs - 1) / bs, bs, 0, stream>>>(partial, kred,
                                                                n_nodes, out);
    } else {
        // fallback: direct global-atomic path
        hipMemsetAsync(d_out, 0, (size_t)out_size * sizeof(float), stream);
        int nb_edges = (n_edges + bs - 1) / bs;
        zbl_edge_atomic<<<nb_edges, bs, 0, stream>>>(x, edge_index, tab, out, n_edges);
    }
}

// Round 6
// 79.236 us; speedup vs baseline: 2.2854x; 1.2399x over previous
//
#include <hip/hip_runtime.h>

#define NELEMS 10
#define W_SHIFT 10             // bucket width = 1024 nodes
#define W 1024
#define MAXBL 128              // max buckets supported by LDS arrays
#define CHUNK 4096             // edges per scatter block
#define EPT 8                  // edges per thread (CHUNK / BS)
#define BS 512
#define PAD 16                 // segment padding (64B lines)
#define SLABCAP (CHUNK + MAXBL * (PAD - 1))   // 6016 LDS staging capacity

// ase covalent radii (Cordero 2008), padded to 119
__constant__ float c_cov[119] = {
    0.2f, 0.31f, 0.28f, 1.28f, 0.96f, 0.84f, 0.76f, 0.71f, 0.66f, 0.57f, 0.58f, 1.66f,
    1.41f, 1.21f, 1.11f, 1.07f, 1.05f, 1.02f, 1.06f, 2.03f, 1.76f, 1.70f, 1.60f, 1.53f,
    1.39f, 1.39f, 1.32f, 1.26f, 1.24f, 1.32f, 1.22f, 1.22f, 1.20f, 1.19f, 1.20f, 1.20f,
    1.16f, 2.20f, 1.95f, 1.90f, 1.75f, 1.64f, 1.54f, 1.47f, 1.46f, 1.42f, 1.39f, 1.45f,
    1.44f, 1.42f, 1.39f, 1.39f, 1.38f, 1.39f, 1.40f, 2.44f, 2.15f, 2.07f, 2.04f, 2.03f,
    2.01f, 1.99f, 1.98f, 1.98f, 1.96f, 1.94f, 1.92f, 1.92f, 1.89f, 1.90f, 1.87f, 1.87f,
    1.75f, 1.70f, 1.62f, 1.51f, 1.44f, 1.41f, 1.36f, 1.36f, 1.32f, 1.45f, 1.46f, 1.48f,
    1.40f, 1.50f, 1.50f, 2.60f, 2.21f, 2.15f, 2.06f, 2.00f, 1.96f, 1.90f, 1.87f, 1.80f,
    1.69f,
    0.2f, 0.2f, 0.2f, 0.2f, 0.2f, 0.2f, 0.2f, 0.2f, 0.2f, 0.2f, 0.2f,
    0.2f, 0.2f, 0.2f, 0.2f, 0.2f, 0.2f, 0.2f, 0.2f, 0.2f, 0.2f, 0.2f
};

// Per-node precompute: argmax of one-hot -> element -> (Z, Z^0.3, cov_radius)
__global__ void zbl_node_prep(const float* __restrict__ node_attrs,
                              const int* __restrict__ atomic_numbers,
                              float4* __restrict__ tab, int n_nodes) {
    int n = blockIdx.x * blockDim.x + threadIdx.x;
    if (n >= n_nodes) return;
    const float* a = node_attrs + (size_t)n * NELEMS;
    int best = 0;
    float bv = a[0];
#pragma unroll
    for (int k = 1; k < NELEMS; ++k) {
        float v = a[k];
        if (v > bv) { bv = v; best = k; }
    }
    int Z = atomic_numbers[best];
    float zf = (float)Z;
    float z03 = powf(zf, 0.3f);
    float cov = c_cov[Z];
    tab[n] = make_float4(zf, z03, cov, 0.0f);
}

__device__ __forceinline__ float zbl_edge_value(float xv, float4 tu, float4 tv) {
    const float inv_a_pref = 1.0f / (0.4543f * 0.529f);
    float roa = xv * (tu.y + tv.y) * inv_a_pref;
    float phi = 0.1818f  * __expf(-3.2f    * roa)
              + 0.5099f  * __expf(-0.9423f * roa)
              + 0.2802f  * __expf(-0.4028f * roa)
              + 0.02817f * __expf(-0.2016f * roa);
    float v = 14.3996f * tu.x * tv.x / xv * phi;
    float rmax = tu.z + tv.z;
    float rr = xv / rmax;
    float rr2 = rr * rr;
    float rr3 = rr2 * rr;
    float rr6 = rr3 * rr3;
    float rr7 = rr6 * rr;
    float rr8 = rr7 * rr;
    float env = 1.0f - 28.0f * rr6 + 48.0f * rr7 - 21.0f * rr8;
    env = (xv < rmax) ? env : 0.0f;
    return 0.5f * v * env;
}

// ---------------- Pass 1: per-block counting sort into a FIXED per-block slab.
// No global placement needed: writeout is a contiguous LDS->global memcpy.
// Per-bucket segments are PAD-aligned; pad entries are (val=0, lr=0) -> inert.
__global__ __launch_bounds__(BS)
void zbl_scatter_local(const float* __restrict__ x,
                       const int* __restrict__ ei,
                       const float4* __restrict__ tab,
                       int n_edges, int nb, int slab,
                       float* __restrict__ valg,
                       unsigned short* __restrict__ lrg,
                       int* __restrict__ offg /*[blk*(nb+1)+b]*/) {
    __shared__ float          val_s[SLABCAP];
    __shared__ unsigned short lr_s[SLABCAP];
    __shared__ int scanv[MAXBL];
    __shared__ int lds_off[MAXBL + 1];
    __shared__ int cursor[MAXBL];

    int blk = blockIdx.x;
    int t = threadIdx.x;
    int e0 = blk * CHUNK;
    int e1 = min(n_edges, e0 + CHUNK);
    const int* recv = ei + n_edges;
    bool full = (e0 + CHUNK <= n_edges);

    for (int i = t; i < nb; i += BS) cursor[i] = 0;
    __syncthreads();

    // ---- count phase (receivers cached in registers on the fast path)
    int rv[EPT];
    if (full) {
        const int4* rp = (const int4*)(recv + e0);
        int4 ra = rp[2 * t], rb = rp[2 * t + 1];
        rv[0] = ra.x; rv[1] = ra.y; rv[2] = ra.z; rv[3] = ra.w;
        rv[4] = rb.x; rv[5] = rb.y; rv[6] = rb.z; rv[7] = rb.w;
#pragma unroll
        for (int i = 0; i < EPT; ++i)
            atomicAdd(&cursor[rv[i] >> W_SHIFT], 1);
    } else {
        for (int e = e0 + t; e < e1; e += BS)
            atomicAdd(&cursor[recv[e] >> W_SHIFT], 1);
    }
    __syncthreads();

    // ---- padded exclusive scan (Hillis-Steele over MAXBL slots)
    if (t < MAXBL) scanv[t] = (t < nb) ? ((cursor[t] + (PAD - 1)) & ~(PAD - 1)) : 0;
    __syncthreads();
    for (int d = 1; d < MAXBL; d <<= 1) {
        int add = 0;
        if (t < MAXBL && t >= d) add = scanv[t - d];
        __syncthreads();
        if (t < MAXBL) scanv[t] += add;
        __syncthreads();
    }
    if (t < MAXBL) lds_off[t + 1] = scanv[t];
    if (t == 0) lds_off[0] = 0;
    __syncthreads();

    int total = lds_off[nb];          // multiple of PAD (16)
    if (t < nb) cursor[t] = lds_off[t];

    // ---- zero staging (pad slots must be val=0, lr=0), vectorized
    int nt4 = total >> 2;
    for (int i = t; i < nt4; i += BS) {
        ((float4*)val_s)[i] = make_float4(0.f, 0.f, 0.f, 0.f);
        ((uint2*)lr_s)[i]   = make_uint2(0u, 0u);
    }
    __syncthreads();

    // ---- place phase (LDS cursor atomics only); vectorized global loads
    if (full) {
        const int4*   sp = (const int4*)(ei + e0);
        const float4* xp = (const float4*)(x + e0);
        int4   sa = sp[2 * t], sb = sp[2 * t + 1];
        float4 xa = xp[2 * t], xb = xp[2 * t + 1];
        int   sv[EPT] = { sa.x, sa.y, sa.z, sa.w, sb.x, sb.y, sb.z, sb.w };
        float xv[EPT] = { xa.x, xa.y, xa.z, xa.w, xb.x, xb.y, xb.z, xb.w };
#pragma unroll
        for (int i = 0; i < EPT; ++i) {
            int r = rv[i];
            float4 tu = tab[sv[i]];
            float4 tw = tab[r];
            float v = zbl_edge_value(xv[i], tu, tw);
            int pos = atomicAdd(&cursor[r >> W_SHIFT], 1);
            val_s[pos] = v;
            lr_s[pos] = (unsigned short)(r & (W - 1));
        }
    } else {
        for (int e = e0 + t; e < e1; e += BS) {
            int s = ei[e];
            int r = recv[e];
            float4 tu = tab[s];
            float4 tw = tab[r];
            float v = zbl_edge_value(x[e], tu, tw);
            int pos = atomicAdd(&cursor[r >> W_SHIFT], 1);
            val_s[pos] = v;
            lr_s[pos] = (unsigned short)(r & (W - 1));
        }
    }
    __syncthreads();

    // ---- contiguous slab writeout (full lines by construction)
    size_t gb = (size_t)blk * slab;
    float4* vdst = (float4*)(valg + gb);
    uint2*  ldst = (uint2*)(lrg + gb);
    for (int i = t; i < nt4; i += BS) {
        vdst[i] = ((float4*)val_s)[i];
        ldst[i] = ((uint2*)lr_s)[i];
    }
    if (t <= nb) offg[blk * (nb + 1) + t] = lds_off[t];
}

// ---------------- Pass 2: per-(bucket, block-slice) segment reduction
// grid = (nb, kred), blockDim = BS. Each wave walks whole segments.
__global__ __launch_bounds__(BS)
void zbl_reduce_seg(const float* __restrict__ valg,
                    const unsigned short* __restrict__ lrg,
                    const int* __restrict__ offg,
                    int nblk, int nb, int kred, int slab,
                    float* __restrict__ partial) {
    __shared__ float acc[W];
    int b = blockIdx.x;
    int j = blockIdx.y;
    int t = threadIdx.x;
    acc[t] = 0.0f;
    acc[t + BS] = 0.0f;
    __syncthreads();

    int stride = (nblk + kred - 1) / kred;
    int blk0 = j * stride;
    int blk1 = min(nblk, blk0 + stride);
    int wave = t >> 6, lane = t & 63;

    for (int blk = blk0 + wave; blk < blk1; blk += (BS / 64)) {
        const int* po = offg + (size_t)blk * (nb + 1) + b;
        int s0 = po[0], s1 = po[1];
        size_t gb = (size_t)blk * slab;
        for (int p = s0 + lane; p < s1; p += 64)
            atomicAdd(&acc[lrg[gb + p]], valg[gb + p]);
    }
    __syncthreads();
    float* dst = partial + (((size_t)b * kred + j) << W_SHIFT);
    dst[t] = acc[t];
    dst[t + BS] = acc[t + BS];
}

// ---------------- Pass 3: sum kred partials per node -> out
__global__ void zbl_combine(const float* __restrict__ partial, int kred,
                            int n_nodes, float* __restrict__ out) {
    int n = blockIdx.x * blockDim.x + threadIdx.x;
    if (n >= n_nodes) return;
    int b = n >> W_SHIFT;
    int t = n & (W - 1);
    float s = 0.0f;
    for (int j = 0; j < kred; ++j)
        s += partial[(((size_t)b * kred + j) << W_SHIFT) + t];
    out[n] = s;
}

// ---------------- Fallback: direct global-atomic path
__global__ void zbl_edge_atomic(const float* __restrict__ x,
                                const int* __restrict__ edge_index,
                                const float4* __restrict__ tab,
                                float* __restrict__ out, int n_edges) {
    int e = blockIdx.x * blockDim.x + threadIdx.x;
    if (e >= n_edges) return;
    int s = edge_index[e];
    int r = edge_index[n_edges + e];
    float4 tu = tab[s];
    float4 tv = tab[r];
    float v = zbl_edge_value(x[e], tu, tv);
#if defined(__HIP_PLATFORM_AMD__)
    unsafeAtomicAdd(out + r, v);
#else
    atomicAdd(out + r, v);
#endif
}

extern "C" void kernel_launch(void* const* d_in, const int* in_sizes, int n_in,
                              void* d_out, int out_size, void* d_ws, size_t ws_size,
                              hipStream_t stream) {
    const float* x              = (const float*)d_in[0];
    const float* node_attrs     = (const float*)d_in[1];
    const int*   edge_index     = (const int*)d_in[2];
    const int*   atomic_numbers = (const int*)d_in[3];
    float*       out            = (float*)d_out;

    int n_edges = in_sizes[0];            // x is [E,1]
    int n_nodes = in_sizes[1] / NELEMS;   // node_attrs is [N,10]
    int nb = (n_nodes + W - 1) / W;       // buckets of 1024 nodes
    int nblk = (n_edges + CHUNK - 1) / CHUNK;
    // runtime slab stride: worst-case padded chunk, 16-element aligned
    int slab = (CHUNK + nb * (PAD - 1) + 15) & ~15;

    char* ws = (char*)d_ws;

    // workspace layout; pick largest kred that fits
    int kred = 0;
    size_t tab_o = 0, val_o = 0, lr_o = 0, offg_o = 0, part_o = 0;
    for (int try_k = 8; try_k >= 1; try_k >>= 1) {
        size_t off = 0;
        auto alloc = [&](size_t bytes) {
            size_t o = off;
            off = (off + bytes + 255) & ~(size_t)255;
            return o;
        };
        tab_o  = alloc((size_t)n_nodes * sizeof(float4));
        val_o  = alloc((size_t)nblk * slab * sizeof(float));
        lr_o   = alloc((size_t)nblk * slab * sizeof(unsigned short));
        offg_o = alloc((size_t)nblk * (nb + 1) * sizeof(int));
        part_o = alloc((size_t)nb * try_k * W * sizeof(float));
        if (off <= ws_size) { kred = try_k; break; }
    }

    float4* tab = (float4*)(ws + tab_o);
    int bs = 256;
    int nb_nodes = (n_nodes + bs - 1) / bs;
    zbl_node_prep<<<nb_nodes, bs, 0, stream>>>(node_attrs, atomic_numbers, tab, n_nodes);

    if (kred >= 1 && nb <= MAXBL && slab <= SLABCAP) {
        float* valg         = (float*)(ws + val_o);
        unsigned short* lrg = (unsigned short*)(ws + lr_o);
        int* offg           = (int*)(ws + offg_o);
        float* partial      = (float*)(ws + part_o);

        zbl_scatter_local<<<nblk, BS, 0, stream>>>(x, edge_index, tab, n_edges,
                                                   nb, slab, valg, lrg, offg);
        zbl_reduce_seg<<<dim3(nb, kred), BS, 0, stream>>>(valg, lrg, offg, nblk,
                                                          nb, kred, slab, partial);
        zbl_combine<<<(n_nodes + bs - 1) / bs, bs, 0, stream>>>(partial, kred,
                                                                n_nodes, out);
    } else {
        // fallback: direct global-atomic path
        hipMemsetAsync(d_out, 0, (size_t)out_size * sizeof(float), stream);
        int nb_edges = (n_edges + bs - 1) / bs;
        zbl_edge_atomic<<<nb_edges, bs, 0, stream>>>(x, edge_index, tab, out, n_edges);
    }
}

// Round 7
// 75.043 us; speedup vs baseline: 2.4131x; 1.0559x over previous
//
#include <hip/hip_runtime.h>

#define NELEMS 10
#define W_SHIFT 10             // bucket width = 1024 nodes
#define W 1024
#define MAXBL 128              // max buckets supported by LDS arrays
#define CHUNK 4096             // edges per scatter block
#define EPT 8                  // edges per thread (CHUNK / BS)
#define BS 512
#define PAD 16                 // segment padding (64B lines)
#define SLABCAP (CHUNK + MAXBL * (PAD - 1))   // 6016 LDS staging capacity
#define INV_A_PREF (1.0f / (0.4543f * 0.529f))

// ase covalent radii (Cordero 2008), padded to 119
__constant__ float c_cov[119] = {
    0.2f, 0.31f, 0.28f, 1.28f, 0.96f, 0.84f, 0.76f, 0.71f, 0.66f, 0.57f, 0.58f, 1.66f,
    1.41f, 1.21f, 1.11f, 1.07f, 1.05f, 1.02f, 1.06f, 2.03f, 1.76f, 1.70f, 1.60f, 1.53f,
    1.39f, 1.39f, 1.32f, 1.26f, 1.24f, 1.32f, 1.22f, 1.22f, 1.20f, 1.19f, 1.20f, 1.20f,
    1.16f, 2.20f, 1.95f, 1.90f, 1.75f, 1.64f, 1.54f, 1.47f, 1.46f, 1.42f, 1.39f, 1.45f,
    1.44f, 1.42f, 1.39f, 1.39f, 1.38f, 1.39f, 1.40f, 2.44f, 2.15f, 2.07f, 2.04f, 2.03f,
    2.01f, 1.99f, 1.98f, 1.98f, 1.96f, 1.94f, 1.92f, 1.92f, 1.89f, 1.90f, 1.87f, 1.87f,
    1.75f, 1.70f, 1.62f, 1.51f, 1.44f, 1.41f, 1.36f, 1.36f, 1.32f, 1.45f, 1.46f, 1.48f,
    1.40f, 1.50f, 1.50f, 2.60f, 2.21f, 2.15f, 2.06f, 2.00f, 1.96f, 1.90f, 1.87f, 1.80f,
    1.69f,
    0.2f, 0.2f, 0.2f, 0.2f, 0.2f, 0.2f, 0.2f, 0.2f, 0.2f, 0.2f, 0.2f,
    0.2f, 0.2f, 0.2f, 0.2f, 0.2f, 0.2f, 0.2f, 0.2f, 0.2f, 0.2f, 0.2f
};

// ---------------- elem table: 10 entries of (Z, Z^0.3, cov, 0)
__global__ void zbl_elem_tab(const int* __restrict__ atomic_numbers,
                             float4* __restrict__ etab_g) {
    int t = threadIdx.x;
    if (t < NELEMS) {
        int Z = atomic_numbers[t];
        float zf = (float)Z;
        etab_g[t] = make_float4(zf, powf(zf, 0.3f), c_cov[Z], 0.0f);
    }
}

// ---------------- per-node elem id (uchar). Block stages 256 rows in LDS.
__global__ __launch_bounds__(256)
void zbl_node_elem(const float* __restrict__ node_attrs,
                   unsigned char* __restrict__ elem, int n_nodes) {
    __shared__ float rows[256 * NELEMS];
    int t = threadIdx.x;
    int n0 = blockIdx.x * 256;
    int nrow = min(256, n_nodes - n0);
    int nflt = nrow * NELEMS;
    const float* src = node_attrs + (size_t)n0 * NELEMS;
    for (int i = t; i < nflt; i += 256) rows[i] = src[i];
    __syncthreads();
    if (t < nrow) {
        const float* a = rows + t * NELEMS;
        int best = 0;
        float bv = a[0];
#pragma unroll
        for (int k = 1; k < NELEMS; ++k) {
            float v = a[k];
            if (v > bv) { bv = v; best = k; }
        }
        elem[n0 + t] = (unsigned char)best;
    }
}

__device__ __forceinline__ float zbl_edge_value_p(float xv, float4 pe) {
    // pe = (A=14.3996*Zu*Zv, B=(zu03+zv03)*INV_A_PREF, C=rmax, -)
    float roa = xv * pe.y;
    float phi = 0.1818f  * __expf(-3.2f    * roa)
              + 0.5099f  * __expf(-0.9423f * roa)
              + 0.2802f  * __expf(-0.4028f * roa)
              + 0.02817f * __expf(-0.2016f * roa);
    float v = pe.x / xv * phi;
    float rr = xv / pe.z;
    float rr2 = rr * rr;
    float rr3 = rr2 * rr;
    float rr6 = rr3 * rr3;
    float rr7 = rr6 * rr;
    float rr8 = rr7 * rr;
    float env = 1.0f - 28.0f * rr6 + 48.0f * rr7 - 21.0f * rr8;
    env = (xv < pe.z) ? env : 0.0f;
    return 0.5f * v * env;
}

// ---------------- Pass 1: per-block counting sort into a FIXED per-block slab.
// Per-bucket segments are PAD-aligned; pad entries are (val=0, lr=0) -> inert.
// Node state gathered as 1-byte elem ids; pair math from a 100-entry LDS table.
__global__ __launch_bounds__(BS)
void zbl_scatter_local(const float* __restrict__ x,
                       const int* __restrict__ ei,
                       const unsigned char* __restrict__ elem,
                       const float4* __restrict__ etab_g,
                       int n_edges, int nb, int slab,
                       float* __restrict__ valg,
                       unsigned short* __restrict__ lrg,
                       int* __restrict__ offg /*[blk*(nb+1)+b]*/) {
    __shared__ float          val_s[SLABCAP];
    __shared__ unsigned short lr_s[SLABCAP];
    __shared__ int scanv[MAXBL];
    __shared__ int lds_off[MAXBL + 1];
    __shared__ int cursor[MAXBL];
    __shared__ float4 etab[NELEMS];
    __shared__ float4 ptab[NELEMS * NELEMS];

    int blk = blockIdx.x;
    int t = threadIdx.x;
    int e0 = blk * CHUNK;
    int e1 = min(n_edges, e0 + CHUNK);
    const int* recv = ei + n_edges;
    bool full = (e0 + CHUNK <= n_edges);

    if (t < NELEMS) etab[t] = etab_g[t];
    for (int i = t; i < nb; i += BS) cursor[i] = 0;
    __syncthreads();
    if (t < NELEMS * NELEMS) {
        float4 u = etab[t / NELEMS];
        float4 v = etab[t % NELEMS];
        ptab[t] = make_float4(14.3996f * u.x * v.x,
                              (u.y + v.y) * INV_A_PREF,
                              u.z + v.z, 0.0f);
    }

    // ---- count phase (receivers cached in registers on the fast path)
    int rv[EPT];
    if (full) {
        const int4* rp = (const int4*)(recv + e0);
        int4 ra = rp[2 * t], rb = rp[2 * t + 1];
        rv[0] = ra.x; rv[1] = ra.y; rv[2] = ra.z; rv[3] = ra.w;
        rv[4] = rb.x; rv[5] = rb.y; rv[6] = rb.z; rv[7] = rb.w;
#pragma unroll
        for (int i = 0; i < EPT; ++i)
            atomicAdd(&cursor[rv[i] >> W_SHIFT], 1);
    } else {
        for (int e = e0 + t; e < e1; e += BS)
            atomicAdd(&cursor[recv[e] >> W_SHIFT], 1);
    }
    __syncthreads();

    // ---- padded exclusive scan (Hillis-Steele over MAXBL slots)
    if (t < MAXBL) scanv[t] = (t < nb) ? ((cursor[t] + (PAD - 1)) & ~(PAD - 1)) : 0;
    __syncthreads();
    for (int d = 1; d < MAXBL; d <<= 1) {
        int add = 0;
        if (t < MAXBL && t >= d) add = scanv[t - d];
        __syncthreads();
        if (t < MAXBL) scanv[t] += add;
        __syncthreads();
    }
    if (t < MAXBL) lds_off[t + 1] = scanv[t];
    if (t == 0) lds_off[0] = 0;
    __syncthreads();

    int total = lds_off[nb];          // multiple of PAD (16)
    if (t < nb) cursor[t] = lds_off[t];

    // ---- zero staging (pad slots must be val=0, lr=0), vectorized
    int nt4 = total >> 2;
    for (int i = t; i < nt4; i += BS) {
        ((float4*)val_s)[i] = make_float4(0.f, 0.f, 0.f, 0.f);
        ((uint2*)lr_s)[i]   = make_uint2(0u, 0u);
    }
    __syncthreads();

    // ---- place phase: hoisted 1-byte gathers, LDS pair-table math
    if (full) {
        const int4*   sp = (const int4*)(ei + e0);
        const float4* xp = (const float4*)(x + e0);
        int4   sa = sp[2 * t], sb = sp[2 * t + 1];
        float4 xa = xp[2 * t], xb = xp[2 * t + 1];
        int   sv[EPT] = { sa.x, sa.y, sa.z, sa.w, sb.x, sb.y, sb.z, sb.w };
        float xv[EPT] = { xa.x, xa.y, xa.z, xa.w, xb.x, xb.y, xb.z, xb.w };
        unsigned char es[EPT], er[EPT];
#pragma unroll
        for (int i = 0; i < EPT; ++i) es[i] = elem[sv[i]];
#pragma unroll
        for (int i = 0; i < EPT; ++i) er[i] = elem[rv[i]];
#pragma unroll
        for (int i = 0; i < EPT; ++i) {
            int r = rv[i];
            float4 pe = ptab[(int)es[i] * NELEMS + (int)er[i]];
            float v = zbl_edge_value_p(xv[i], pe);
            int pos = atomicAdd(&cursor[r >> W_SHIFT], 1);
            val_s[pos] = v;
            lr_s[pos] = (unsigned short)(r & (W - 1));
        }
    } else {
        for (int e = e0 + t; e < e1; e += BS) {
            int s = ei[e];
            int r = recv[e];
            float4 pe = ptab[(int)elem[s] * NELEMS + (int)elem[r]];
            float v = zbl_edge_value_p(x[e], pe);
            int pos = atomicAdd(&cursor[r >> W_SHIFT], 1);
            val_s[pos] = v;
            lr_s[pos] = (unsigned short)(r & (W - 1));
        }
    }
    __syncthreads();

    // ---- contiguous slab writeout (full lines by construction)
    size_t gb = (size_t)blk * slab;
    float4* vdst = (float4*)(valg + gb);
    uint2*  ldst = (uint2*)(lrg + gb);
    for (int i = t; i < nt4; i += BS) {
        vdst[i] = ((float4*)val_s)[i];
        ldst[i] = ((uint2*)lr_s)[i];
    }
    if (t <= nb) offg[blk * (nb + 1) + t] = lds_off[t];
}

// ---------------- Pass 2: per-(bucket, slab-slice) segment reduction.
// 16-lane sub-waves each own a slab; float4/ushort4 loads (4 entries/lane).
__global__ __launch_bounds__(BS)
void zbl_reduce_seg(const float* __restrict__ valg,
                    const unsigned short* __restrict__ lrg,
                    const int* __restrict__ offg,
                    int nblk, int nb, int kred, int slab,
                    float* __restrict__ partial) {
    __shared__ float acc[W];
    int b = blockIdx.x;
    int j = blockIdx.y;
    int t = threadIdx.x;
    acc[t] = 0.0f;
    acc[t + BS] = 0.0f;
    __syncthreads();

    int stride = (nblk + kred - 1) / kred;
    int blk0 = j * stride;
    int blk1 = min(nblk, blk0 + stride);
    int wave = t >> 6, lane = t & 63;
    int sw = lane >> 4, li = lane & 15;           // 4 sub-waves of 16 lanes
    const int NSW = (BS / 64) * 4;                // 32 concurrent sub-waves

    for (int blk = blk0 + wave * 4 + sw; blk < blk1; blk += NSW) {
        const int* po = offg + (size_t)blk * (nb + 1) + b;
        int s0 = po[0], s1 = po[1];               // multiples of 16
        size_t gb = (size_t)blk * slab;
        const float4*  v4 = (const float4*)(valg + gb);
        const ushort4* l4 = (const ushort4*)(lrg + gb);
        for (int q = (s0 >> 2) + li; q < (s1 >> 2); q += 16) {
            float4  v = v4[q];
            ushort4 l = l4[q];
            atomicAdd(&acc[l.x], v.x);
            atomicAdd(&acc[l.y], v.y);
            atomicAdd(&acc[l.z], v.z);
            atomicAdd(&acc[l.w], v.w);
        }
    }
    __syncthreads();
    float* dst = partial + (((size_t)b * kred + j) << W_SHIFT);
    dst[t] = acc[t];
    dst[t + BS] = acc[t + BS];
}

// ---------------- Pass 3: sum kred partials per node -> out
__global__ void zbl_combine(const float* __restrict__ partial, int kred,
                            int n_nodes, float* __restrict__ out) {
    int n = blockIdx.x * blockDim.x + threadIdx.x;
    if (n >= n_nodes) return;
    int b = n >> W_SHIFT;
    int t = n & (W - 1);
    float s = 0.0f;
    for (int j = 0; j < kred; ++j)
        s += partial[(((size_t)b * kred + j) << W_SHIFT) + t];
    out[n] = s;
}

// ---------------- Fallback: direct global-atomic path
__global__ void zbl_edge_atomic(const float* __restrict__ x,
                                const int* __restrict__ edge_index,
                                const unsigned char* __restrict__ elem,
                                const float4* __restrict__ etab_g,
                                float* __restrict__ out, int n_edges) {
    int e = blockIdx.x * blockDim.x + threadIdx.x;
    if (e >= n_edges) return;
    int s = edge_index[e];
    int r = edge_index[n_edges + e];
    float4 u = etab_g[elem[s]];
    float4 w = etab_g[elem[r]];
    float4 pe = make_float4(14.3996f * u.x * w.x, (u.y + w.y) * INV_A_PREF,
                            u.z + w.z, 0.0f);
    float v = zbl_edge_value_p(x[e], pe);
#if defined(__HIP_PLATFORM_AMD__)
    unsafeAtomicAdd(out + r, v);
#else
    atomicAdd(out + r, v);
#endif
}

extern "C" void kernel_launch(void* const* d_in, const int* in_sizes, int n_in,
                              void* d_out, int out_size, void* d_ws, size_t ws_size,
                              hipStream_t stream) {
    const float* x              = (const float*)d_in[0];
    const float* node_attrs     = (const float*)d_in[1];
    const int*   edge_index     = (const int*)d_in[2];
    const int*   atomic_numbers = (const int*)d_in[3];
    float*       out            = (float*)d_out;

    int n_edges = in_sizes[0];            // x is [E,1]
    int n_nodes = in_sizes[1] / NELEMS;   // node_attrs is [N,10]
    int nb = (n_nodes + W - 1) / W;       // buckets of 1024 nodes
    int nblk = (n_edges + CHUNK - 1) / CHUNK;
    int slab = (CHUNK + nb * (PAD - 1) + 15) & ~15;

    char* ws = (char*)d_ws;

    // workspace layout; pick largest kred that fits
    int kred = 0;
    size_t elem_o = 0, etab_o = 0, val_o = 0, lr_o = 0, offg_o = 0, part_o = 0;
    for (int try_k = 16; try_k >= 1; try_k >>= 1) {
        size_t off = 0;
        auto alloc = [&](size_t bytes) {
            size_t o = off;
            off = (off + bytes + 255) & ~(size_t)255;
            return o;
        };
        elem_o = alloc((size_t)n_nodes);
        etab_o = alloc(NELEMS * sizeof(float4));
        val_o  = alloc((size_t)nblk * slab * sizeof(float));
        lr_o   = alloc((size_t)nblk * slab * sizeof(unsigned short));
        offg_o = alloc((size_t)nblk * (nb + 1) * sizeof(int));
        part_o = alloc((size_t)nb * try_k * W * sizeof(float));
        if (off <= ws_size) { kred = try_k; break; }
    }

    unsigned char* elem = (unsigned char*)(ws + elem_o);
    float4* etab_g      = (float4*)(ws + etab_o);

    zbl_elem_tab<<<1, 64, 0, stream>>>(atomic_numbers, etab_g);
    int nb_nodes = (n_nodes + 255) / 256;
    zbl_node_elem<<<nb_nodes, 256, 0, stream>>>(node_attrs, elem, n_nodes);

    if (kred >= 1 && nb <= MAXBL && slab <= SLABCAP) {
        float* valg         = (float*)(ws + val_o);
        unsigned short* lrg = (unsigned short*)(ws + lr_o);
        int* offg           = (int*)(ws + offg_o);
        float* partial      = (float*)(ws + part_o);

        zbl_scatter_local<<<nblk, BS, 0, stream>>>(x, edge_index, elem, etab_g,
                                                   n_edges, nb, slab,
                                                   valg, lrg, offg);
        zbl_reduce_seg<<<dim3(nb, kred), BS, 0, stream>>>(valg, lrg, offg, nblk,
                                                          nb, kred, slab, partial);
        zbl_combine<<<(n_nodes + 255) / 256, 256, 0, stream>>>(partial, kred,
                                                               n_nodes, out);
    } else {
        // fallback: direct global-atomic path
        hipMemsetAsync(d_out, 0, (size_t)out_size * sizeof(float), stream);
        int nb_edges = (n_edges + 255) / 256;
        zbl_edge_atomic<<<nb_edges, 256, 0, stream>>>(x, edge_index, elem, etab_g,
                                                      out, n_edges);
    }
}

// Round 8
// 72.676 us; speedup vs baseline: 2.4917x; 1.0326x over previous
//
#include <hip/hip_runtime.h>

#define NELEMS 10
#define W_SHIFT 10             // bucket width = 1024 nodes
#define W 1024
#define MAXBL 128              // max buckets supported by LDS arrays
#define CHUNK 4096             // edges per scatter block
#define EPT 8                  // edges per thread (CHUNK / BS)
#define BS 512
#define PAD 16                 // segment padding (64B lines)
#define SLABCAP (CHUNK + MAXBL * (PAD - 1))   // 6016 LDS staging capacity
#define INV_A_PREF (1.0f / (0.4543f * 0.529f))

// ase covalent radii (Cordero 2008), padded to 119
__constant__ float c_cov[119] = {
    0.2f, 0.31f, 0.28f, 1.28f, 0.96f, 0.84f, 0.76f, 0.71f, 0.66f, 0.57f, 0.58f, 1.66f,
    1.41f, 1.21f, 1.11f, 1.07f, 1.05f, 1.02f, 1.06f, 2.03f, 1.76f, 1.70f, 1.60f, 1.53f,
    1.39f, 1.39f, 1.32f, 1.26f, 1.24f, 1.32f, 1.22f, 1.22f, 1.20f, 1.19f, 1.20f, 1.20f,
    1.16f, 2.20f, 1.95f, 1.90f, 1.75f, 1.64f, 1.54f, 1.47f, 1.46f, 1.42f, 1.39f, 1.45f,
    1.44f, 1.42f, 1.39f, 1.39f, 1.38f, 1.39f, 1.40f, 2.44f, 2.15f, 2.07f, 2.04f, 2.03f,
    2.01f, 1.99f, 1.98f, 1.98f, 1.96f, 1.94f, 1.92f, 1.92f, 1.89f, 1.90f, 1.87f, 1.87f,
    1.75f, 1.70f, 1.62f, 1.51f, 1.44f, 1.41f, 1.36f, 1.36f, 1.32f, 1.45f, 1.46f, 1.48f,
    1.40f, 1.50f, 1.50f, 2.60f, 2.21f, 2.15f, 2.06f, 2.00f, 1.96f, 1.90f, 1.87f, 1.80f,
    1.69f,
    0.2f, 0.2f, 0.2f, 0.2f, 0.2f, 0.2f, 0.2f, 0.2f, 0.2f, 0.2f, 0.2f,
    0.2f, 0.2f, 0.2f, 0.2f, 0.2f, 0.2f, 0.2f, 0.2f, 0.2f, 0.2f, 0.2f
};

// ---------------- per-node elem id (uchar); block 0 also builds the
// 10-entry (Z, Z^0.3, cov) element table used by later kernels.
__global__ __launch_bounds__(256)
void zbl_node_elem(const float* __restrict__ node_attrs,
                   const int* __restrict__ atomic_numbers,
                   unsigned char* __restrict__ elem,
                   float4* __restrict__ etab_g, int n_nodes) {
    __shared__ float rows[256 * NELEMS];
    int t = threadIdx.x;
    if (blockIdx.x == 0 && t < NELEMS) {
        int Z = atomic_numbers[t];
        float zf = (float)Z;
        etab_g[t] = make_float4(zf, powf(zf, 0.3f), c_cov[Z], 0.0f);
    }
    int n0 = blockIdx.x * 256;
    int nrow = min(256, n_nodes - n0);
    int nflt = nrow * NELEMS;
    const float* src = node_attrs + (size_t)n0 * NELEMS;
    for (int i = t; i < nflt; i += 256) rows[i] = src[i];
    __syncthreads();
    if (t < nrow) {
        const float* a = rows + t * NELEMS;
        int best = 0;
        float bv = a[0];
#pragma unroll
        for (int k = 1; k < NELEMS; ++k) {
            float v = a[k];
            if (v > bv) { bv = v; best = k; }
        }
        elem[n0 + t] = (unsigned char)best;
    }
}

__device__ __forceinline__ float zbl_edge_value_p(float xv, float A, float B,
                                                  float C) {
    float roa = xv * B;
    float phi = 0.1818f  * __expf(-3.2f    * roa)
              + 0.5099f  * __expf(-0.9423f * roa)
              + 0.2802f  * __expf(-0.4028f * roa)
              + 0.02817f * __expf(-0.2016f * roa);
    float v = A / xv * phi;
    float rr = xv / C;
    float rr2 = rr * rr;
    float rr3 = rr2 * rr;
    float rr6 = rr3 * rr3;
    float rr7 = rr6 * rr;
    float rr8 = rr7 * rr;
    float env = 1.0f - 28.0f * rr6 + 48.0f * rr7 - 21.0f * rr8;
    env = (xv < C) ? env : 0.0f;
    return 0.5f * v * env;
}

// ---------------- Pass 1: per-block counting sort into a FIXED per-block slab.
// All global loads hoisted into one burst; wave-0 shuffle scan (no barriers
// inside); 3 __syncthreads total on the fast path.
__global__ __launch_bounds__(BS)
void zbl_scatter_local(const float* __restrict__ x,
                       const int* __restrict__ ei,
                       const unsigned char* __restrict__ elem,
                       const float4* __restrict__ etab_g,
                       int n_edges, int nb, int slab,
                       float* __restrict__ valg,
                       unsigned short* __restrict__ lrg,
                       int* __restrict__ offg /*[blk*(nb+1)+b]*/) {
    __shared__ float          val_s[SLABCAP];
    __shared__ unsigned short lr_s[SLABCAP];
    __shared__ int   lds_off[MAXBL + 1];
    __shared__ int   cursor[MAXBL];
    __shared__ float ptabA[NELEMS * NELEMS];
    __shared__ float ptabB[NELEMS * NELEMS];
    __shared__ float ptabC[NELEMS * NELEMS];

    int blk = blockIdx.x;
    int t = threadIdx.x;
    int e0 = blk * CHUNK;
    int e1 = min(n_edges, e0 + CHUNK);
    const int* recv = ei + n_edges;
    bool full = (e0 + CHUNK <= n_edges);

    // ---- zero staging up-front (pads must be val=0, lr=0); no dependencies
    for (int i = t; i < (SLABCAP >> 2); i += BS) {
        ((float4*)val_s)[i] = make_float4(0.f, 0.f, 0.f, 0.f);
        ((uint2*)lr_s)[i]   = make_uint2(0u, 0u);
    }
    if (t < MAXBL) cursor[t] = 0;
    // pair tables from global etab (L2-resident, 100 entries)
    if (t < NELEMS * NELEMS) {
        float4 u = etab_g[t / NELEMS];
        float4 v = etab_g[t % NELEMS];
        ptabA[t] = 14.3996f * u.x * v.x;
        ptabB[t] = (u.y + v.y) * INV_A_PREF;
        ptabC[t] = u.z + v.z;
    }
    __syncthreads();   // barrier 1: staging + cursor + ptab ready

    // ---- hoisted load burst (max MLP), then count
    int rv[EPT], sv[EPT];
    float xv[EPT];
    unsigned char es[EPT], er[EPT];
    if (full) {
        const int4*   rp = (const int4*)(recv + e0);
        const int4*   sp = (const int4*)(ei + e0);
        const float4* xp = (const float4*)(x + e0);
        int4 ra = rp[2 * t], rb = rp[2 * t + 1];
        int4 sa = sp[2 * t], sb = sp[2 * t + 1];
        float4 xa = xp[2 * t], xb = xp[2 * t + 1];
        rv[0] = ra.x; rv[1] = ra.y; rv[2] = ra.z; rv[3] = ra.w;
        rv[4] = rb.x; rv[5] = rb.y; rv[6] = rb.z; rv[7] = rb.w;
        sv[0] = sa.x; sv[1] = sa.y; sv[2] = sa.z; sv[3] = sa.w;
        sv[4] = sb.x; sv[5] = sb.y; sv[6] = sb.z; sv[7] = sb.w;
        xv[0] = xa.x; xv[1] = xa.y; xv[2] = xa.z; xv[3] = xa.w;
        xv[4] = xb.x; xv[5] = xb.y; xv[6] = xb.z; xv[7] = xb.w;
#pragma unroll
        for (int i = 0; i < EPT; ++i) es[i] = elem[sv[i]];
#pragma unroll
        for (int i = 0; i < EPT; ++i) er[i] = elem[rv[i]];
#pragma unroll
        for (int i = 0; i < EPT; ++i)
            atomicAdd(&cursor[rv[i] >> W_SHIFT], 1);
    } else {
        for (int e = e0 + t; e < e1; e += BS)
            atomicAdd(&cursor[recv[e] >> W_SHIFT], 1);
    }
    __syncthreads();   // barrier 2: counts ready

    // ---- wave-0 shuffle scan over 128 bucket slots (no barriers inside)
    if (t < 64) {
        int a = (t < nb)      ? ((cursor[t]      + (PAD - 1)) & ~(PAD - 1)) : 0;
        int b = (t + 64 < nb) ? ((cursor[t + 64] + (PAD - 1)) & ~(PAD - 1)) : 0;
        int a0 = a, b0 = b;
#pragma unroll
        for (int d = 1; d < 64; d <<= 1) {
            int va = __shfl_up(a, d);
            int vb = __shfl_up(b, d);
            if (t >= d) { a += va; b += vb; }
        }
        int totA = __shfl(a, 63);
        b += totA;
        lds_off[t + 1]  = a;
        lds_off[t + 65] = b;
        cursor[t]       = a - a0;      // exclusive offset = segment start
        cursor[t + 64]  = b - b0;
        if (t == 0) lds_off[0] = 0;
    }
    __syncthreads();   // barrier 3: offsets + cursors ready

    int total = lds_off[nb];          // multiple of PAD (16)

    // ---- place phase: registers only + LDS
    if (full) {
#pragma unroll
        for (int i = 0; i < EPT; ++i) {
            int r = rv[i];
            int pi = (int)es[i] * NELEMS + (int)er[i];
            float v = zbl_edge_value_p(xv[i], ptabA[pi], ptabB[pi], ptabC[pi]);
            int pos = atomicAdd(&cursor[r >> W_SHIFT], 1);
            val_s[pos] = v;
            lr_s[pos] = (unsigned short)(r & (W - 1));
        }
    } else {
        for (int e = e0 + t; e < e1; e += BS) {
            int s = ei[e];
            int r = recv[e];
            int pi = (int)elem[s] * NELEMS + (int)elem[r];
            float v = zbl_edge_value_p(x[e], ptabA[pi], ptabB[pi], ptabC[pi]);
            int pos = atomicAdd(&cursor[r >> W_SHIFT], 1);
            val_s[pos] = v;
            lr_s[pos] = (unsigned short)(r & (W - 1));
        }
    }
    __syncthreads();   // barrier 4: staging complete

    // ---- contiguous slab writeout (full lines by construction)
    size_t gb = (size_t)blk * slab;
    float4* vdst = (float4*)(valg + gb);
    uint2*  ldst = (uint2*)(lrg + gb);
    int nt4 = total >> 2;
    for (int i = t; i < nt4; i += BS) {
        vdst[i] = ((float4*)val_s)[i];
        ldst[i] = ((uint2*)lr_s)[i];
    }
    if (t <= nb) offg[blk * (nb + 1) + t] = lds_off[t];
}

// ---------------- Pass 2: per-(bucket, slab-slice) segment reduction.
// 16-lane sub-waves each own a slab; float4/ushort4 loads (4 entries/lane).
__global__ __launch_bounds__(BS)
void zbl_reduce_seg(const float* __restrict__ valg,
                    const unsigned short* __restrict__ lrg,
                    const int* __restrict__ offg,
                    int nblk, int nb, int kred, int slab,
                    float* __restrict__ partial) {
    __shared__ float acc[W];
    int b = blockIdx.x;
    int j = blockIdx.y;
    int t = threadIdx.x;
    acc[t] = 0.0f;
    acc[t + BS] = 0.0f;
    __syncthreads();

    int stride = (nblk + kred - 1) / kred;
    int blk0 = j * stride;
    int blk1 = min(nblk, blk0 + stride);
    int wave = t >> 6, lane = t & 63;
    int sw = lane >> 4, li = lane & 15;           // 4 sub-waves of 16 lanes
    const int NSW = (BS / 64) * 4;                // 32 concurrent sub-waves

    for (int blk = blk0 + wave * 4 + sw; blk < blk1; blk += NSW) {
        const int* po = offg + (size_t)blk * (nb + 1) + b;
        int s0 = po[0], s1 = po[1];               // multiples of 16
        size_t gb = (size_t)blk * slab;
        const float4*  v4 = (const float4*)(valg + gb);
        const ushort4* l4 = (const ushort4*)(lrg + gb);
        for (int q = (s0 >> 2) + li; q < (s1 >> 2); q += 16) {
            float4  v = v4[q];
            ushort4 l = l4[q];
            atomicAdd(&acc[l.x], v.x);
            atomicAdd(&acc[l.y], v.y);
            atomicAdd(&acc[l.z], v.z);
            atomicAdd(&acc[l.w], v.w);
        }
    }
    __syncthreads();
    float* dst = partial + (((size_t)b * kred + j) << W_SHIFT);
    dst[t] = acc[t];
    dst[t + BS] = acc[t + BS];
}

// ---------------- Pass 3: sum kred partials per node -> out (float4)
__global__ void zbl_combine(const float* __restrict__ partial, int kred,
                            int n_nodes, float* __restrict__ out) {
    int q = blockIdx.x * blockDim.x + threadIdx.x;   // float4 index
    int n = q << 2;
    if (n >= n_nodes) return;
    int b = n >> W_SHIFT;
    int t = n & (W - 1);
    float4 s = make_float4(0.f, 0.f, 0.f, 0.f);
    for (int j = 0; j < kred; ++j) {
        const float4* p =
            (const float4*)(partial + (((size_t)b * kred + j) << W_SHIFT) + t);
        float4 v = *p;
        s.x += v.x; s.y += v.y; s.z += v.z; s.w += v.w;
    }
    if (n + 3 < n_nodes) {
        *(float4*)(out + n) = s;
    } else {
        out[n] = s.x;
        if (n + 1 < n_nodes) out[n + 1] = s.y;
        if (n + 2 < n_nodes) out[n + 2] = s.z;
    }
}

// ---------------- Fallback: direct global-atomic path
__global__ void zbl_edge_atomic(const float* __restrict__ x,
                                const int* __restrict__ edge_index,
                                const unsigned char* __restrict__ elem,
                                const float4* __restrict__ etab_g,
                                float* __restrict__ out, int n_edges) {
    int e = blockIdx.x * blockDim.x + threadIdx.x;
    if (e >= n_edges) return;
    int s = edge_index[e];
    int r = edge_index[n_edges + e];
    float4 u = etab_g[elem[s]];
    float4 w = etab_g[elem[r]];
    float v = zbl_edge_value_p(x[e], 14.3996f * u.x * w.x,
                               (u.y + w.y) * INV_A_PREF, u.z + w.z);
#if defined(__HIP_PLATFORM_AMD__)
    unsafeAtomicAdd(out + r, v);
#else
    atomicAdd(out + r, v);
#endif
}

extern "C" void kernel_launch(void* const* d_in, const int* in_sizes, int n_in,
                              void* d_out, int out_size, void* d_ws, size_t ws_size,
                              hipStream_t stream) {
    const float* x              = (const float*)d_in[0];
    const float* node_attrs     = (const float*)d_in[1];
    const int*   edge_index     = (const int*)d_in[2];
    const int*   atomic_numbers = (const int*)d_in[3];
    float*       out            = (float*)d_out;

    int n_edges = in_sizes[0];            // x is [E,1]
    int n_nodes = in_sizes[1] / NELEMS;   // node_attrs is [N,10]
    int nb = (n_nodes + W - 1) / W;       // buckets of 1024 nodes
    int nblk = (n_edges + CHUNK - 1) / CHUNK;
    int slab = (CHUNK + nb * (PAD - 1) + 15) & ~15;

    char* ws = (char*)d_ws;

    // workspace layout; pick largest kred that fits
    int kred = 0;
    size_t elem_o = 0, etab_o = 0, val_o = 0, lr_o = 0, offg_o = 0, part_o = 0;
    for (int try_k = 16; try_k >= 1; try_k >>= 1) {
        size_t off = 0;
        auto alloc = [&](size_t bytes) {
            size_t o = off;
            off = (off + bytes + 255) & ~(size_t)255;
            return o;
        };
        elem_o = alloc((size_t)n_nodes);
        etab_o = alloc(NELEMS * sizeof(float4));
        val_o  = alloc((size_t)nblk * slab * sizeof(float));
        lr_o   = alloc((size_t)nblk * slab * sizeof(unsigned short));
        offg_o = alloc((size_t)nblk * (nb + 1) * sizeof(int));
        part_o = alloc((size_t)nb * try_k * W * sizeof(float));
        if (off <= ws_size) { kred = try_k; break; }
    }

    unsigned char* elem = (unsigned char*)(ws + elem_o);
    float4* etab_g      = (float4*)(ws + etab_o);

    int nb_nodes = (n_nodes + 255) / 256;
    zbl_node_elem<<<nb_nodes, 256, 0, stream>>>(node_attrs, atomic_numbers,
                                                elem, etab_g, n_nodes);

    if (kred >= 1 && nb <= MAXBL && slab <= SLABCAP) {
        float* valg         = (float*)(ws + val_o);
        unsigned short* lrg = (unsigned short*)(ws + lr_o);
        int* offg           = (int*)(ws + offg_o);
        float* partial      = (float*)(ws + part_o);

        zbl_scatter_local<<<nblk, BS, 0, stream>>>(x, edge_index, elem, etab_g,
                                                   n_edges, nb, slab,
                                                   valg, lrg, offg);
        zbl_reduce_seg<<<dim3(nb, kred), BS, 0, stream>>>(valg, lrg, offg, nblk,
                                                          nb, kred, slab, partial);
        int nq = (n_nodes + 3) >> 2;
        zbl_combine<<<(nq + 255) / 256, 256, 0, stream>>>(partial, kred,
                                                          n_nodes, out);
    } else {
        // fallback: direct global-atomic path
        hipMemsetAsync(d_out, 0, (size_t)out_size * sizeof(float), stream);
        int nb_edges = (n_edges + 255) / 256;
        zbl_edge_atomic<<<nb_edges, 256, 0, stream>>>(x, edge_index, elem, etab_g,
                                                      out, n_edges);
    }
}

// Round 9
// 59.996 us; speedup vs baseline: 3.0183x; 1.2113x over previous
//
#include <hip/hip_runtime.h>

#define NELEMS 10
#define W_SHIFT 10             // bucket width = 1024 nodes
#define W 1024
#define MAXBL 128              // max buckets supported by LDS arrays
#define CHUNK 4096             // edges per sort block
#define EPT 8                  // edges per thread (CHUNK / BS)
#define BS 512
#define PAD 4                  // segment padding (vector alignment only)
#define SLABCAP (CHUNK + MAXBL * (PAD - 1))   // 4480
#define PKCAP 51200            // 50KB packed elem capacity (<=102400 nodes)
#define CHUNKA 4096            // edges per iteration in kernel A
#define INV_A_PREF (1.0f / (0.4543f * 0.529f))

// ase covalent radii (Cordero 2008), padded to 119
__constant__ float c_cov[119] = {
    0.2f, 0.31f, 0.28f, 1.28f, 0.96f, 0.84f, 0.76f, 0.71f, 0.66f, 0.57f, 0.58f, 1.66f,
    1.41f, 1.21f, 1.11f, 1.07f, 1.05f, 1.02f, 1.06f, 2.03f, 1.76f, 1.70f, 1.60f, 1.53f,
    1.39f, 1.39f, 1.32f, 1.26f, 1.24f, 1.32f, 1.22f, 1.22f, 1.20f, 1.19f, 1.20f, 1.20f,
    1.16f, 2.20f, 1.95f, 1.90f, 1.75f, 1.64f, 1.54f, 1.47f, 1.46f, 1.42f, 1.39f, 1.45f,
    1.44f, 1.42f, 1.39f, 1.39f, 1.38f, 1.39f, 1.40f, 2.44f, 2.15f, 2.07f, 2.04f, 2.03f,
    2.01f, 1.99f, 1.98f, 1.98f, 1.96f, 1.94f, 1.92f, 1.92f, 1.89f, 1.90f, 1.87f, 1.87f,
    1.75f, 1.70f, 1.62f, 1.51f, 1.44f, 1.41f, 1.36f, 1.36f, 1.32f, 1.45f, 1.46f, 1.48f,
    1.40f, 1.50f, 1.50f, 2.60f, 2.21f, 2.15f, 2.06f, 2.00f, 1.96f, 1.90f, 1.87f, 1.80f,
    1.69f,
    0.2f, 0.2f, 0.2f, 0.2f, 0.2f, 0.2f, 0.2f, 0.2f, 0.2f, 0.2f, 0.2f,
    0.2f, 0.2f, 0.2f, 0.2f, 0.2f, 0.2f, 0.2f, 0.2f, 0.2f, 0.2f, 0.2f
};

// ---------------- per-node elem id: bytes (fallback) + 4-bit packed (kernel A);
// block 0 also builds the 10-entry (Z, Z^0.3, cov) element table.
__global__ __launch_bounds__(256)
void zbl_node_elem(const float* __restrict__ node_attrs,
                   const int* __restrict__ atomic_numbers,
                   unsigned char* __restrict__ elem,
                   unsigned char* __restrict__ packed,
                   float4* __restrict__ etab_g, int n_nodes) {
    __shared__ float rows[256 * NELEMS];
    __shared__ unsigned char earr[256];
    int t = threadIdx.x;
    if (blockIdx.x == 0 && t < NELEMS) {
        int Z = atomic_numbers[t];
        float zf = (float)Z;
        etab_g[t] = make_float4(zf, powf(zf, 0.3f), c_cov[Z], 0.0f);
    }
    int n0 = blockIdx.x * 256;
    int nrow = min(256, n_nodes - n0);
    int nflt = nrow * NELEMS;
    const float* src = node_attrs + (size_t)n0 * NELEMS;
    for (int i = t; i < nflt; i += 256) rows[i] = src[i];
    __syncthreads();
    if (t < nrow) {
        const float* a = rows + t * NELEMS;
        int best = 0;
        float bv = a[0];
#pragma unroll
        for (int k = 1; k < NELEMS; ++k) {
            float v = a[k];
            if (v > bv) { bv = v; best = k; }
        }
        earr[t] = (unsigned char)best;
        elem[n0 + t] = (unsigned char)best;
    }
    __syncthreads();
    if (t < 128 && 2 * t < nrow) {
        unsigned char lo = earr[2 * t];
        unsigned char hi = (2 * t + 1 < nrow) ? earr[2 * t + 1] : 0;
        packed[(n0 >> 1) + t] = (unsigned char)(lo | (hi << 4));
    }
}

__device__ __forceinline__ float zbl_edge_value_p(float xv, float A, float B,
                                                  float C) {
    float roa = xv * B;
    float phi = 0.1818f  * __expf(-3.2f    * roa)
              + 0.5099f  * __expf(-0.9423f * roa)
              + 0.2802f  * __expf(-0.4028f * roa)
              + 0.02817f * __expf(-0.2016f * roa);
    float v = A / xv * phi;
    float rr = xv / C;
    float rr2 = rr * rr;
    float rr3 = rr2 * rr;
    float rr6 = rr3 * rr3;
    float rr7 = rr6 * rr;
    float rr8 = rr7 * rr;
    float env = 1.0f - 28.0f * rr6 + 48.0f * rr7 - 21.0f * rr8;
    env = (xv < C) ? env : 0.0f;
    return 0.5f * v * env;
}

// ---------------- Kernel A: per-edge ZBL value, LDS-resident packed elem map.
// One barrier total; barrier-free grid-stride main loop; all loads coalesced,
// all gathers hit LDS.
__global__ __launch_bounds__(BS)
void zbl_edge_val(const float* __restrict__ x,
                  const int* __restrict__ ei,
                  const unsigned char* __restrict__ packed,
                  const float4* __restrict__ etab_g,
                  int n_edges, int n_nodes,
                  float* __restrict__ vale) {
    __shared__ unsigned char pk[PKCAP];
    __shared__ float ptabA[NELEMS * NELEMS];
    __shared__ float ptabB[NELEMS * NELEMS];
    __shared__ float ptabC[NELEMS * NELEMS];

    int t = threadIdx.x;
    int npk = (n_nodes + 1) >> 1;
    // coalesced copy of the packed map into LDS (uint32 granularity)
    {
        const unsigned int* ps = (const unsigned int*)packed;
        unsigned int* pd = (unsigned int*)pk;
        int nw = npk >> 2;
        for (int i = t; i < nw; i += BS) pd[i] = ps[i];
        for (int i = (nw << 2) + t; i < npk; i += BS) pk[i] = packed[i];
    }
    if (t < NELEMS * NELEMS) {
        float4 u = etab_g[t / NELEMS];
        float4 v = etab_g[t % NELEMS];
        ptabA[t] = 14.3996f * u.x * v.x;
        ptabB[t] = (u.y + v.y) * INV_A_PREF;
        ptabC[t] = u.z + v.z;
    }
    __syncthreads();

    const int* send = ei;
    const int* recv = ei + n_edges;

    for (int base = blockIdx.x * CHUNKA; base < n_edges;
         base += gridDim.x * CHUNKA) {
        if (base + CHUNKA <= n_edges) {
            const int4*   sp = (const int4*)(send + base);
            const int4*   rp = (const int4*)(recv + base);
            const float4* xp = (const float4*)(x + base);
            int4 sa = sp[2 * t], sb = sp[2 * t + 1];
            int4 ra = rp[2 * t], rb = rp[2 * t + 1];
            float4 xa = xp[2 * t], xb = xp[2 * t + 1];
            int   sv[EPT] = { sa.x, sa.y, sa.z, sa.w, sb.x, sb.y, sb.z, sb.w };
            int   rv[EPT] = { ra.x, ra.y, ra.z, ra.w, rb.x, rb.y, rb.z, rb.w };
            float xv[EPT] = { xa.x, xa.y, xa.z, xa.w, xb.x, xb.y, xb.z, xb.w };
            float o[EPT];
#pragma unroll
            for (int i = 0; i < EPT; ++i) {
                int s = sv[i], r = rv[i];
                int es = (pk[s >> 1] >> ((s & 1) << 2)) & 15;
                int er = (pk[r >> 1] >> ((r & 1) << 2)) & 15;
                int pi = es * NELEMS + er;
                o[i] = zbl_edge_value_p(xv[i], ptabA[pi], ptabB[pi], ptabC[pi]);
            }
            float4* vo = (float4*)(vale + base);
            vo[2 * t]     = make_float4(o[0], o[1], o[2], o[3]);
            vo[2 * t + 1] = make_float4(o[4], o[5], o[6], o[7]);
        } else {
            for (int e = base + t; e < n_edges; e += BS) {
                int s = send[e], r = recv[e];
                int es = (pk[s >> 1] >> ((s & 1) << 2)) & 15;
                int er = (pk[r >> 1] >> ((r & 1) << 2)) & 15;
                int pi = es * NELEMS + er;
                vale[e] = zbl_edge_value_p(x[e], ptabA[pi], ptabB[pi], ptabC[pi]);
            }
        }
    }
}

// ---------------- Kernel B: counting sort of (val, lr) into fixed per-block
// slabs. No gathers, no flops: recv + vale coalesced in, contiguous slab out.
__global__ __launch_bounds__(BS)
void zbl_sort(const float* __restrict__ vale,
              const int* __restrict__ recv,
              int n_edges, int nb, int slab,
              float* __restrict__ valg,
              unsigned short* __restrict__ lrg,
              int* __restrict__ offg /*[blk*(nb+1)+b]*/) {
    __shared__ float          val_s[SLABCAP];
    __shared__ unsigned short lr_s[SLABCAP];
    __shared__ int lds_off[MAXBL + 1];
    __shared__ int cursor[MAXBL];

    int blk = blockIdx.x;
    int t = threadIdx.x;
    int e0 = blk * CHUNK;
    int e1 = min(n_edges, e0 + CHUNK);
    bool full = (e0 + CHUNK <= n_edges);

    // zero staging up-front (pads must be val=0, lr=0)
    for (int i = t; i < (SLABCAP >> 2); i += BS) {
        ((float4*)val_s)[i] = make_float4(0.f, 0.f, 0.f, 0.f);
        ((uint2*)lr_s)[i]   = make_uint2(0u, 0u);
    }
    if (t < MAXBL) cursor[t] = 0;
    __syncthreads();   // barrier 1

    // hoisted load burst + count
    int rv[EPT];
    float ov[EPT];
    if (full) {
        const int4*   rp = (const int4*)(recv + e0);
        const float4* vp = (const float4*)(vale + e0);
        int4 ra = rp[2 * t], rb = rp[2 * t + 1];
        float4 va = vp[2 * t], vb = vp[2 * t + 1];
        rv[0] = ra.x; rv[1] = ra.y; rv[2] = ra.z; rv[3] = ra.w;
        rv[4] = rb.x; rv[5] = rb.y; rv[6] = rb.z; rv[7] = rb.w;
        ov[0] = va.x; ov[1] = va.y; ov[2] = va.z; ov[3] = va.w;
        ov[4] = vb.x; ov[5] = vb.y; ov[6] = vb.z; ov[7] = vb.w;
#pragma unroll
        for (int i = 0; i < EPT; ++i)
            atomicAdd(&cursor[rv[i] >> W_SHIFT], 1);
    } else {
        for (int e = e0 + t; e < e1; e += BS)
            atomicAdd(&cursor[recv[e] >> W_SHIFT], 1);
    }
    __syncthreads();   // barrier 2

    // wave-0 shuffle scan over 128 bucket slots (no internal barriers)
    if (t < 64) {
        int a = (t < nb)      ? ((cursor[t]      + (PAD - 1)) & ~(PAD - 1)) : 0;
        int b = (t + 64 < nb) ? ((cursor[t + 64] + (PAD - 1)) & ~(PAD - 1)) : 0;
        int a0 = a, b0 = b;
#pragma unroll
        for (int d = 1; d < 64; d <<= 1) {
            int va = __shfl_up(a, d);
            int vb = __shfl_up(b, d);
            if (t >= d) { a += va; b += vb; }
        }
        int totA = __shfl(a, 63);
        b += totA;
        lds_off[t + 1]  = a;
        lds_off[t + 65] = b;
        cursor[t]       = a - a0;
        cursor[t + 64]  = b - b0;
        if (t == 0) lds_off[0] = 0;
    }
    __syncthreads();   // barrier 3

    int total = lds_off[nb];          // multiple of PAD (4)

    // place phase (LDS cursor atomics only)
    if (full) {
#pragma unroll
        for (int i = 0; i < EPT; ++i) {
            int r = rv[i];
            int pos = atomicAdd(&cursor[r >> W_SHIFT], 1);
            val_s[pos] = ov[i];
            lr_s[pos] = (unsigned short)(r & (W - 1));
        }
    } else {
        for (int e = e0 + t; e < e1; e += BS) {
            int r = recv[e];
            int pos = atomicAdd(&cursor[r >> W_SHIFT], 1);
            val_s[pos] = vale[e];
            lr_s[pos] = (unsigned short)(r & (W - 1));
        }
    }
    __syncthreads();   // barrier 4

    // contiguous slab writeout
    size_t gb = (size_t)blk * slab;
    float4* vdst = (float4*)(valg + gb);
    uint2*  ldst = (uint2*)(lrg + gb);
    int nt4 = total >> 2;
    for (int i = t; i < nt4; i += BS) {
        vdst[i] = ((float4*)val_s)[i];
        ldst[i] = ((uint2*)lr_s)[i];
    }
    if (t <= nb) offg[blk * (nb + 1) + t] = lds_off[t];
}

// ---------------- Pass 3: per-(bucket, slab-slice) segment reduction.
// 16-lane sub-waves each own a slab; float4/ushort4 loads (4 entries/lane).
__global__ __launch_bounds__(BS)
void zbl_reduce_seg(const float* __restrict__ valg,
                    const unsigned short* __restrict__ lrg,
                    const int* __restrict__ offg,
                    int nblk, int nb, int kred, int slab,
                    float* __restrict__ partial) {
    __shared__ float acc[W];
    int b = blockIdx.x;
    int j = blockIdx.y;
    int t = threadIdx.x;
    acc[t] = 0.0f;
    acc[t + BS] = 0.0f;
    __syncthreads();

    int stride = (nblk + kred - 1) / kred;
    int blk0 = j * stride;
    int blk1 = min(nblk, blk0 + stride);
    int wave = t >> 6, lane = t & 63;
    int sw = lane >> 4, li = lane & 15;           // 4 sub-waves of 16 lanes
    const int NSW = (BS / 64) * 4;                // 32 concurrent sub-waves

    for (int blk = blk0 + wave * 4 + sw; blk < blk1; blk += NSW) {
        const int* po = offg + (size_t)blk * (nb + 1) + b;
        int s0 = po[0], s1 = po[1];               // multiples of 4
        size_t gb = (size_t)blk * slab;
        const float4*  v4 = (const float4*)(valg + gb);
        const ushort4* l4 = (const ushort4*)(lrg + gb);
        for (int q = (s0 >> 2) + li; q < (s1 >> 2); q += 16) {
            float4  v = v4[q];
            ushort4 l = l4[q];
            atomicAdd(&acc[l.x], v.x);
            atomicAdd(&acc[l.y], v.y);
            atomicAdd(&acc[l.z], v.z);
            atomicAdd(&acc[l.w], v.w);
        }
    }
    __syncthreads();
    float* dst = partial + (((size_t)b * kred + j) << W_SHIFT);
    dst[t] = acc[t];
    dst[t + BS] = acc[t + BS];
}

// ---------------- Pass 4: sum kred partials per node -> out (float4)
__global__ void zbl_combine(const float* __restrict__ partial, int kred,
                            int n_nodes, float* __restrict__ out) {
    int q = blockIdx.x * blockDim.x + threadIdx.x;   // float4 index
    int n = q << 2;
    if (n >= n_nodes) return;
    int b = n >> W_SHIFT;
    int t = n & (W - 1);
    float4 s = make_float4(0.f, 0.f, 0.f, 0.f);
    for (int j = 0; j < kred; ++j) {
        const float4* p =
            (const float4*)(partial + (((size_t)b * kred + j) << W_SHIFT) + t);
        float4 v = *p;
        s.x += v.x; s.y += v.y; s.z += v.z; s.w += v.w;
    }
    if (n + 3 < n_nodes) {
        *(float4*)(out + n) = s;
    } else {
        out[n] = s.x;
        if (n + 1 < n_nodes) out[n + 1] = s.y;
        if (n + 2 < n_nodes) out[n + 2] = s.z;
    }
}

// ---------------- Fallback: direct global-atomic path
__global__ void zbl_edge_atomic(const float* __restrict__ x,
                                const int* __restrict__ edge_index,
                                const unsigned char* __restrict__ elem,
                                const float4* __restrict__ etab_g,
                                float* __restrict__ out, int n_edges) {
    int e = blockIdx.x * blockDim.x + threadIdx.x;
    if (e >= n_edges) return;
    int s = edge_index[e];
    int r = edge_index[n_edges + e];
    float4 u = etab_g[elem[s]];
    float4 w = etab_g[elem[r]];
    float v = zbl_edge_value_p(x[e], 14.3996f * u.x * w.x,
                               (u.y + w.y) * INV_A_PREF, u.z + w.z);
#if defined(__HIP_PLATFORM_AMD__)
    unsafeAtomicAdd(out + r, v);
#else
    atomicAdd(out + r, v);
#endif
}

extern "C" void kernel_launch(void* const* d_in, const int* in_sizes, int n_in,
                              void* d_out, int out_size, void* d_ws, size_t ws_size,
                              hipStream_t stream) {
    const float* x              = (const float*)d_in[0];
    const float* node_attrs     = (const float*)d_in[1];
    const int*   edge_index     = (const int*)d_in[2];
    const int*   atomic_numbers = (const int*)d_in[3];
    float*       out            = (float*)d_out;

    int n_edges = in_sizes[0];            // x is [E,1]
    int n_nodes = in_sizes[1] / NELEMS;   // node_attrs is [N,10]
    int nb = (n_nodes + W - 1) / W;       // buckets of 1024 nodes
    int nblk = (n_edges + CHUNK - 1) / CHUNK;
    int slab = (CHUNK + nb * (PAD - 1) + 3) & ~3;

    char* ws = (char*)d_ws;

    // workspace layout; pick largest kred that fits
    int kred = 0;
    size_t elem_o = 0, pk_o = 0, etab_o = 0, vale_o = 0,
           val_o = 0, lr_o = 0, offg_o = 0, part_o = 0;
    for (int try_k = 16; try_k >= 1; try_k >>= 1) {
        size_t off = 0;
        auto alloc = [&](size_t bytes) {
            size_t o = off;
            off = (off + bytes + 255) & ~(size_t)255;
            return o;
        };
        elem_o = alloc((size_t)n_nodes);
        pk_o   = alloc((size_t)(n_nodes + 1) / 2);
        etab_o = alloc(NELEMS * sizeof(float4));
        vale_o = alloc((size_t)n_edges * sizeof(float));
        val_o  = alloc((size_t)nblk * slab * sizeof(float));
        lr_o   = alloc((size_t)nblk * slab * sizeof(unsigned short));
        offg_o = alloc((size_t)nblk * (nb + 1) * sizeof(int));
        part_o = alloc((size_t)nb * try_k * W * sizeof(float));
        if (off <= ws_size) { kred = try_k; break; }
    }

    unsigned char* elem   = (unsigned char*)(ws + elem_o);
    unsigned char* packed = (unsigned char*)(ws + pk_o);
    float4* etab_g        = (float4*)(ws + etab_o);

    int nb_nodes = (n_nodes + 255) / 256;
    zbl_node_elem<<<nb_nodes, 256, 0, stream>>>(node_attrs, atomic_numbers,
                                                elem, packed, etab_g, n_nodes);

    bool fast_ok = (kred >= 1) && (nb <= MAXBL) && (slab <= SLABCAP) &&
                   (((n_nodes + 1) >> 1) <= PKCAP);

    if (fast_ok) {
        float* vale         = (float*)(ws + vale_o);
        float* valg         = (float*)(ws + val_o);
        unsigned short* lrg = (unsigned short*)(ws + lr_o);
        int* offg           = (int*)(ws + offg_o);
        float* partial      = (float*)(ws + part_o);
        const int* recv     = edge_index + n_edges;

        int gridA = nblk < 768 ? nblk : 768;
        zbl_edge_val<<<gridA, BS, 0, stream>>>(x, edge_index, packed, etab_g,
                                               n_edges, n_nodes, vale);
        zbl_sort<<<nblk, BS, 0, stream>>>(vale, recv, n_edges, nb, slab,
                                          valg, lrg, offg);
        zbl_reduce_seg<<<dim3(nb, kred), BS, 0, stream>>>(valg, lrg, offg, nblk,
                                                          nb, kred, slab, partial);
        int nq = (n_nodes + 3) >> 2;
        zbl_combine<<<(nq + 255) / 256, 256, 0, stream>>>(partial, kred,
                                                          n_nodes, out);
    } else {
        // fallback: direct global-atomic path
        hipMemsetAsync(d_out, 0, (size_t)out_size * sizeof(float), stream);
        int nb_edges = (n_edges + 255) / 256;
        zbl_edge_atomic<<<nb_edges, 256, 0, stream>>>(x, edge_index, elem, etab_g,
                                                      out, n_edges);
    }
}

// Round 10
// 59.251 us; speedup vs baseline: 3.0562x; 1.0126x over previous
//
#include <hip/hip_runtime.h>

#define NELEMS 10
#define W_SHIFT 10             // bucket width = 1024 nodes
#define W 1024
#define MAXBL 128              // max buckets supported by LDS arrays
#define CHUNK 4096             // edges per sort block
#define EPT 8                  // edges per thread (CHUNK / BS)
#define BS 512
#define PAD 4                  // segment padding (vector alignment only)
#define SLABCAP (CHUNK + MAXBL * (PAD - 1))   // 4480
#define PKCAP 50176            // 49KB packed elem capacity (<=100352 nodes)
#define INV_A_PREF (1.0f / (0.4543f * 0.529f))

// ase covalent radii (Cordero 2008), padded to 119
__constant__ float c_cov[119] = {
    0.2f, 0.31f, 0.28f, 1.28f, 0.96f, 0.84f, 0.76f, 0.71f, 0.66f, 0.57f, 0.58f, 1.66f,
    1.41f, 1.21f, 1.11f, 1.07f, 1.05f, 1.02f, 1.06f, 2.03f, 1.76f, 1.70f, 1.60f, 1.53f,
    1.39f, 1.39f, 1.32f, 1.26f, 1.24f, 1.32f, 1.22f, 1.22f, 1.20f, 1.19f, 1.20f, 1.20f,
    1.16f, 2.20f, 1.95f, 1.90f, 1.75f, 1.64f, 1.54f, 1.47f, 1.46f, 1.42f, 1.39f, 1.45f,
    1.44f, 1.42f, 1.39f, 1.39f, 1.38f, 1.39f, 1.40f, 2.44f, 2.15f, 2.07f, 2.04f, 2.03f,
    2.01f, 1.99f, 1.98f, 1.98f, 1.96f, 1.94f, 1.92f, 1.92f, 1.89f, 1.90f, 1.87f, 1.87f,
    1.75f, 1.70f, 1.62f, 1.51f, 1.44f, 1.41f, 1.36f, 1.36f, 1.32f, 1.45f, 1.46f, 1.48f,
    1.40f, 1.50f, 1.50f, 2.60f, 2.21f, 2.15f, 2.06f, 2.00f, 1.96f, 1.90f, 1.87f, 1.80f,
    1.69f,
    0.2f, 0.2f, 0.2f, 0.2f, 0.2f, 0.2f, 0.2f, 0.2f, 0.2f, 0.2f, 0.2f,
    0.2f, 0.2f, 0.2f, 0.2f, 0.2f, 0.2f, 0.2f, 0.2f, 0.2f, 0.2f, 0.2f
};

// ---------------- per-node elem id: bytes (fallback) + 4-bit packed (fused);
// block 0 also builds the 10-entry (Z, Z^0.3, cov) element table.
__global__ __launch_bounds__(256)
void zbl_node_elem(const float* __restrict__ node_attrs,
                   const int* __restrict__ atomic_numbers,
                   unsigned char* __restrict__ elem,
                   unsigned char* __restrict__ packed,
                   float4* __restrict__ etab_g, int n_nodes) {
    __shared__ float rows[256 * NELEMS];
    __shared__ unsigned char earr[256];
    int t = threadIdx.x;
    if (blockIdx.x == 0 && t < NELEMS) {
        int Z = atomic_numbers[t];
        float zf = (float)Z;
        etab_g[t] = make_float4(zf, powf(zf, 0.3f), c_cov[Z], 0.0f);
    }
    int n0 = blockIdx.x * 256;
    int nrow = min(256, n_nodes - n0);
    int nflt = nrow * NELEMS;
    const float* src = node_attrs + (size_t)n0 * NELEMS;
    for (int i = t; i < nflt; i += 256) rows[i] = src[i];
    __syncthreads();
    if (t < nrow) {
        const float* a = rows + t * NELEMS;
        int best = 0;
        float bv = a[0];
#pragma unroll
        for (int k = 1; k < NELEMS; ++k) {
            float v = a[k];
            if (v > bv) { bv = v; best = k; }
        }
        earr[t] = (unsigned char)best;
        elem[n0 + t] = (unsigned char)best;
    }
    __syncthreads();
    if (t < 128 && 2 * t < nrow) {
        unsigned char lo = earr[2 * t];
        unsigned char hi = (2 * t + 1 < nrow) ? earr[2 * t + 1] : 0;
        packed[(n0 >> 1) + t] = (unsigned char)(lo | (hi << 4));
    }
}

__device__ __forceinline__ float zbl_edge_value_p(float xv, float A, float B,
                                                  float C) {
    float roa = xv * B;
    float phi = 0.1818f  * __expf(-3.2f    * roa)
              + 0.5099f  * __expf(-0.9423f * roa)
              + 0.2802f  * __expf(-0.4028f * roa)
              + 0.02817f * __expf(-0.2016f * roa);
    float v = A / xv * phi;
    float rr = xv / C;
    float rr2 = rr * rr;
    float rr3 = rr2 * rr;
    float rr6 = rr3 * rr3;
    float rr7 = rr6 * rr;
    float rr8 = rr7 * rr;
    float env = 1.0f - 28.0f * rr6 + 48.0f * rr7 - 21.0f * rr8;
    env = (xv < C) ? env : 0.0f;
    return 0.5f * v * env;
}

// ---------------- Fused: per-edge ZBL value + counting sort into fixed
// per-block slabs. Elem map is 4-bit packed and LDS-resident (random gathers
// hit LDS, not global). ~79KB LDS -> 2 blocks/CU, 16 waves.
__global__ __launch_bounds__(BS)
void zbl_fused(const float* __restrict__ x,
               const int* __restrict__ ei,
               const unsigned char* __restrict__ packed,
               const float4* __restrict__ etab_g,
               int n_edges, int n_nodes, int nb, int slab,
               float* __restrict__ valg,
               unsigned short* __restrict__ lrg,
               int* __restrict__ offg /*[blk*(nb+1)+b]*/) {
    __shared__ unsigned char  pk[PKCAP];
    __shared__ float          val_s[SLABCAP];
    __shared__ unsigned short lr_s[SLABCAP];
    __shared__ int   lds_off[MAXBL + 1];
    __shared__ int   cursor[MAXBL];
    __shared__ float ptabA[NELEMS * NELEMS];
    __shared__ float ptabB[NELEMS * NELEMS];
    __shared__ float ptabC[NELEMS * NELEMS];

    int blk = blockIdx.x;
    int t = threadIdx.x;
    int e0 = blk * CHUNK;
    int e1 = min(n_edges, e0 + CHUNK);
    const int* send = ei;
    const int* recv = ei + n_edges;
    bool full = (e0 + CHUNK <= n_edges);

    if (t < MAXBL) cursor[t] = 0;
    __syncthreads();   // barrier 0: cursor zeroed (cheap, nothing in flight)

    // ---- overlapped phase: pk copy + staging zero + ptab + load burst + count
    {
        const unsigned int* ps = (const unsigned int*)packed;
        unsigned int* pd = (unsigned int*)pk;
        int npk = (n_nodes + 1) >> 1;
        int nw = npk >> 2;
        for (int i = t; i < nw; i += BS) pd[i] = ps[i];
        for (int i = (nw << 2) + t; i < npk; i += BS) pk[i] = packed[i];
    }
    for (int i = t; i < (SLABCAP >> 2); i += BS) {
        ((float4*)val_s)[i] = make_float4(0.f, 0.f, 0.f, 0.f);
        ((uint2*)lr_s)[i]   = make_uint2(0u, 0u);
    }
    if (t < NELEMS * NELEMS) {
        float4 u = etab_g[t / NELEMS];
        float4 v = etab_g[t % NELEMS];
        ptabA[t] = 14.3996f * u.x * v.x;
        ptabB[t] = (u.y + v.y) * INV_A_PREF;
        ptabC[t] = u.z + v.z;
    }

    int rv[EPT], sv[EPT];
    float xv[EPT];
    if (full) {
        const int4*   rp = (const int4*)(recv + e0);
        const int4*   sp = (const int4*)(send + e0);
        const float4* xp = (const float4*)(x + e0);
        int4 ra = rp[2 * t], rb = rp[2 * t + 1];
        int4 sa = sp[2 * t], sb = sp[2 * t + 1];
        float4 xa = xp[2 * t], xb = xp[2 * t + 1];
        rv[0] = ra.x; rv[1] = ra.y; rv[2] = ra.z; rv[3] = ra.w;
        rv[4] = rb.x; rv[5] = rb.y; rv[6] = rb.z; rv[7] = rb.w;
        sv[0] = sa.x; sv[1] = sa.y; sv[2] = sa.z; sv[3] = sa.w;
        sv[4] = sb.x; sv[5] = sb.y; sv[6] = sb.z; sv[7] = sb.w;
        xv[0] = xa.x; xv[1] = xa.y; xv[2] = xa.z; xv[3] = xa.w;
        xv[4] = xb.x; xv[5] = xb.y; xv[6] = xb.z; xv[7] = xb.w;
#pragma unroll
        for (int i = 0; i < EPT; ++i)
            atomicAdd(&cursor[rv[i] >> W_SHIFT], 1);
    } else {
        for (int e = e0 + t; e < e1; e += BS)
            atomicAdd(&cursor[recv[e] >> W_SHIFT], 1);
    }
    __syncthreads();   // barrier 1: pk + staging + ptab + counts ready

    // ---- wave-0 shuffle scan over 128 bucket slots (no internal barriers)
    if (t < 64) {
        int a = (t < nb)      ? ((cursor[t]      + (PAD - 1)) & ~(PAD - 1)) : 0;
        int b = (t + 64 < nb) ? ((cursor[t + 64] + (PAD - 1)) & ~(PAD - 1)) : 0;
        int a0 = a, b0 = b;
#pragma unroll
        for (int d = 1; d < 64; d <<= 1) {
            int va = __shfl_up(a, d);
            int vb = __shfl_up(b, d);
            if (t >= d) { a += va; b += vb; }
        }
        int totA = __shfl(a, 63);
        b += totA;
        lds_off[t + 1]  = a;
        lds_off[t + 65] = b;
        cursor[t]       = a - a0;
        cursor[t + 64]  = b - b0;
        if (t == 0) lds_off[0] = 0;
    }
    __syncthreads();   // barrier 2: offsets + cursors ready

    int total = lds_off[nb];          // multiple of PAD (4)

    // ---- compute + place phase (LDS nibble gathers + LDS cursor atomics)
    if (full) {
#pragma unroll
        for (int i = 0; i < EPT; ++i) {
            int s = sv[i], r = rv[i];
            int es = (pk[s >> 1] >> ((s & 1) << 2)) & 15;
            int er = (pk[r >> 1] >> ((r & 1) << 2)) & 15;
            int pi = es * NELEMS + er;
            float v = zbl_edge_value_p(xv[i], ptabA[pi], ptabB[pi], ptabC[pi]);
            int pos = atomicAdd(&cursor[r >> W_SHIFT], 1);
            val_s[pos] = v;
            lr_s[pos] = (unsigned short)(r & (W - 1));
        }
    } else {
        for (int e = e0 + t; e < e1; e += BS) {
            int s = send[e], r = recv[e];
            int es = (pk[s >> 1] >> ((s & 1) << 2)) & 15;
            int er = (pk[r >> 1] >> ((r & 1) << 2)) & 15;
            int pi = es * NELEMS + er;
            float v = zbl_edge_value_p(x[e], ptabA[pi], ptabB[pi], ptabC[pi]);
            int pos = atomicAdd(&cursor[r >> W_SHIFT], 1);
            val_s[pos] = v;
            lr_s[pos] = (unsigned short)(r & (W - 1));
        }
    }
    __syncthreads();   // barrier 3: staging complete

    // ---- contiguous slab writeout (full lines by construction)
    size_t gb = (size_t)blk * slab;
    float4* vdst = (float4*)(valg + gb);
    uint2*  ldst = (uint2*)(lrg + gb);
    int nt4 = total >> 2;
    for (int i = t; i < nt4; i += BS) {
        vdst[i] = ((float4*)val_s)[i];
        ldst[i] = ((uint2*)lr_s)[i];
    }
    if (t <= nb) offg[blk * (nb + 1) + t] = lds_off[t];
}

// ---------------- Pass 3: per-(bucket, slab-slice) segment reduction.
// 16-lane sub-waves each own a slab; float4/ushort4 loads (4 entries/lane).
__global__ __launch_bounds__(BS)
void zbl_reduce_seg(const float* __restrict__ valg,
                    const unsigned short* __restrict__ lrg,
                    const int* __restrict__ offg,
                    int nblk, int nb, int kred, int slab,
                    float* __restrict__ partial) {
    __shared__ float acc[W];
    int b = blockIdx.x;
    int j = blockIdx.y;
    int t = threadIdx.x;
    acc[t] = 0.0f;
    acc[t + BS] = 0.0f;
    __syncthreads();

    int stride = (nblk + kred - 1) / kred;
    int blk0 = j * stride;
    int blk1 = min(nblk, blk0 + stride);
    int wave = t >> 6, lane = t & 63;
    int sw = lane >> 4, li = lane & 15;           // 4 sub-waves of 16 lanes
    const int NSW = (BS / 64) * 4;                // 32 concurrent sub-waves

    for (int blk = blk0 + wave * 4 + sw; blk < blk1; blk += NSW) {
        const int* po = offg + (size_t)blk * (nb + 1) + b;
        int s0 = po[0], s1 = po[1];               // multiples of 4
        size_t gb = (size_t)blk * slab;
        const float4*  v4 = (const float4*)(valg + gb);
        const ushort4* l4 = (const ushort4*)(lrg + gb);
        for (int q = (s0 >> 2) + li; q < (s1 >> 2); q += 16) {
            float4  v = v4[q];
            ushort4 l = l4[q];
            atomicAdd(&acc[l.x], v.x);
            atomicAdd(&acc[l.y], v.y);
            atomicAdd(&acc[l.z], v.z);
            atomicAdd(&acc[l.w], v.w);
        }
    }
    __syncthreads();
    float* dst = partial + (((size_t)b * kred + j) << W_SHIFT);
    dst[t] = acc[t];
    dst[t + BS] = acc[t + BS];
}

// ---------------- Pass 4: sum kred partials per node -> out (float4)
__global__ void zbl_combine(const float* __restrict__ partial, int kred,
                            int n_nodes, float* __restrict__ out) {
    int q = blockIdx.x * blockDim.x + threadIdx.x;   // float4 index
    int n = q << 2;
    if (n >= n_nodes) return;
    int b = n >> W_SHIFT;
    int t = n & (W - 1);
    float4 s = make_float4(0.f, 0.f, 0.f, 0.f);
    for (int j = 0; j < kred; ++j) {
        const float4* p =
            (const float4*)(partial + (((size_t)b * kred + j) << W_SHIFT) + t);
        float4 v = *p;
        s.x += v.x; s.y += v.y; s.z += v.z; s.w += v.w;
    }
    if (n + 3 < n_nodes) {
        *(float4*)(out + n) = s;
    } else {
        out[n] = s.x;
        if (n + 1 < n_nodes) out[n + 1] = s.y;
        if (n + 2 < n_nodes) out[n + 2] = s.z;
    }
}

// ---------------- Fallback: direct global-atomic path
__global__ void zbl_edge_atomic(const float* __restrict__ x,
                                const int* __restrict__ edge_index,
                                const unsigned char* __restrict__ elem,
                                const float4* __restrict__ etab_g,
                                float* __restrict__ out, int n_edges) {
    int e = blockIdx.x * blockDim.x + threadIdx.x;
    if (e >= n_edges) return;
    int s = edge_index[e];
    int r = edge_index[n_edges + e];
    float4 u = etab_g[elem[s]];
    float4 w = etab_g[elem[r]];
    float v = zbl_edge_value_p(x[e], 14.3996f * u.x * w.x,
                               (u.y + w.y) * INV_A_PREF, u.z + w.z);
#if defined(__HIP_PLATFORM_AMD__)
    unsafeAtomicAdd(out + r, v);
#else
    atomicAdd(out + r, v);
#endif
}

extern "C" void kernel_launch(void* const* d_in, const int* in_sizes, int n_in,
                              void* d_out, int out_size, void* d_ws, size_t ws_size,
                              hipStream_t stream) {
    const float* x              = (const float*)d_in[0];
    const float* node_attrs     = (const float*)d_in[1];
    const int*   edge_index     = (const int*)d_in[2];
    const int*   atomic_numbers = (const int*)d_in[3];
    float*       out            = (float*)d_out;

    int n_edges = in_sizes[0];            // x is [E,1]
    int n_nodes = in_sizes[1] / NELEMS;   // node_attrs is [N,10]
    int nb = (n_nodes + W - 1) / W;       // buckets of 1024 nodes
    int nblk = (n_edges + CHUNK - 1) / CHUNK;
    int slab = (CHUNK + nb * (PAD - 1) + 3) & ~3;

    char* ws = (char*)d_ws;

    // workspace layout; pick largest kred that fits
    int kred = 0;
    size_t elem_o = 0, pk_o = 0, etab_o = 0,
           val_o = 0, lr_o = 0, offg_o = 0, part_o = 0;
    for (int try_k = 16; try_k >= 1; try_k >>= 1) {
        size_t off = 0;
        auto alloc = [&](size_t bytes) {
            size_t o = off;
            off = (off + bytes + 255) & ~(size_t)255;
            return o;
        };
        elem_o = alloc((size_t)n_nodes);
        pk_o   = alloc((size_t)(n_nodes + 1) / 2);
        etab_o = alloc(NELEMS * sizeof(float4));
        val_o  = alloc((size_t)nblk * slab * sizeof(float));
        lr_o   = alloc((size_t)nblk * slab * sizeof(unsigned short));
        offg_o = alloc((size_t)nblk * (nb + 1) * sizeof(int));
        part_o = alloc((size_t)nb * try_k * W * sizeof(float));
        if (off <= ws_size) { kred = try_k; break; }
    }

    unsigned char* elem   = (unsigned char*)(ws + elem_o);
    unsigned char* packed = (unsigned char*)(ws + pk_o);
    float4* etab_g        = (float4*)(ws + etab_o);

    int nb_nodes = (n_nodes + 255) / 256;
    zbl_node_elem<<<nb_nodes, 256, 0, stream>>>(node_attrs, atomic_numbers,
                                                elem, packed, etab_g, n_nodes);

    bool fast_ok = (kred >= 1) && (nb <= MAXBL) && (slab <= SLABCAP) &&
                   (((n_nodes + 1) >> 1) <= PKCAP);

    if (fast_ok) {
        float* valg         = (float*)(ws + val_o);
        unsigned short* lrg = (unsigned short*)(ws + lr_o);
        int* offg           = (int*)(ws + offg_o);
        float* partial      = (float*)(ws + part_o);

        zbl_fused<<<nblk, BS, 0, stream>>>(x, edge_index, packed, etab_g,
                                           n_edges, n_nodes, nb, slab,
                                           valg, lrg, offg);
        zbl_reduce_seg<<<dim3(nb, kred), BS, 0, stream>>>(valg, lrg, offg, nblk,
                                                          nb, kred, slab, partial);
        int nq = (n_nodes + 3) >> 2;
        zbl_combine<<<(nq + 255) / 256, 256, 0, stream>>>(partial, kred,
                                                          n_nodes, out);
    } else {
        // fallback: direct global-atomic path
        hipMemsetAsync(d_out, 0, (size_t)out_size * sizeof(float), stream);
        int nb_edges = (n_edges + 255) / 256;
        zbl_edge_atomic<<<nb_edges, 256, 0, stream>>>(x, edge_index, elem, etab_g,
                                                      out, n_edges);
    }
}

// Round 11
// 57.862 us; speedup vs baseline: 3.1296x; 1.0240x over previous
//
#include <hip/hip_runtime.h>

#define NELEMS 10
#define W_SHIFT 10             // bucket width = 1024 nodes
#define W 1024
#define MAXBL 128              // max buckets supported by LDS arrays
#define CHUNK 4096             // edges per sort chunk
#define EPT 8                  // edges per thread (CHUNK / BS)
#define BS 512
#define PAD 4                  // segment padding (vector alignment only)
#define SLABCAP (CHUNK + MAXBL * (PAD - 1))   // 4480
#define PKCAP 50176            // 49KB packed elem capacity (<=100352 nodes)
#define GRIDP 512              // persistent blocks (2 per CU)
#define INV_A_PREF (1.0f / (0.4543f * 0.529f))

// ase covalent radii (Cordero 2008), padded to 119
__constant__ float c_cov[119] = {
    0.2f, 0.31f, 0.28f, 1.28f, 0.96f, 0.84f, 0.76f, 0.71f, 0.66f, 0.57f, 0.58f, 1.66f,
    1.41f, 1.21f, 1.11f, 1.07f, 1.05f, 1.02f, 1.06f, 2.03f, 1.76f, 1.70f, 1.60f, 1.53f,
    1.39f, 1.39f, 1.32f, 1.26f, 1.24f, 1.32f, 1.22f, 1.22f, 1.20f, 1.19f, 1.20f, 1.20f,
    1.16f, 2.20f, 1.95f, 1.90f, 1.75f, 1.64f, 1.54f, 1.47f, 1.46f, 1.42f, 1.39f, 1.45f,
    1.44f, 1.42f, 1.39f, 1.39f, 1.38f, 1.39f, 1.40f, 2.44f, 2.15f, 2.07f, 2.04f, 2.03f,
    2.01f, 1.99f, 1.98f, 1.98f, 1.96f, 1.94f, 1.92f, 1.92f, 1.89f, 1.90f, 1.87f, 1.87f,
    1.75f, 1.70f, 1.62f, 1.51f, 1.44f, 1.41f, 1.36f, 1.36f, 1.32f, 1.45f, 1.46f, 1.48f,
    1.40f, 1.50f, 1.50f, 2.60f, 2.21f, 2.15f, 2.06f, 2.00f, 1.96f, 1.90f, 1.87f, 1.80f,
    1.69f,
    0.2f, 0.2f, 0.2f, 0.2f, 0.2f, 0.2f, 0.2f, 0.2f, 0.2f, 0.2f, 0.2f,
    0.2f, 0.2f, 0.2f, 0.2f, 0.2f, 0.2f, 0.2f, 0.2f, 0.2f, 0.2f, 0.2f
};

// ---------------- per-node elem id: bytes (fallback) + 4-bit packed (fused);
// block 0 also builds the 10-entry (Z, Z^0.3, cov) element table.
__global__ __launch_bounds__(256)
void zbl_node_elem(const float* __restrict__ node_attrs,
                   const int* __restrict__ atomic_numbers,
                   unsigned char* __restrict__ elem,
                   unsigned char* __restrict__ packed,
                   float4* __restrict__ etab_g, int n_nodes) {
    __shared__ float rows[256 * 11];          // stride 11: bank-conflict-free
    __shared__ unsigned char earr[256];
    int t = threadIdx.x;
    if (blockIdx.x == 0 && t < NELEMS) {
        int Z = atomic_numbers[t];
        float zf = (float)Z;
        etab_g[t] = make_float4(zf, powf(zf, 0.3f), c_cov[Z], 0.0f);
    }
    int n0 = blockIdx.x * 256;
    int nrow = min(256, n_nodes - n0);
    int nflt = nrow * NELEMS;
    const float* src = node_attrs + (size_t)n0 * NELEMS;
    for (int i = t; i < nflt; i += 256) {
        int rr = i / NELEMS, cc = i - rr * NELEMS;
        rows[rr * 11 + cc] = src[i];
    }
    __syncthreads();
    if (t < nrow) {
        const float* a = rows + t * 11;
        int best = 0;
        float bv = a[0];
#pragma unroll
        for (int k = 1; k < NELEMS; ++k) {
            float v = a[k];
            if (v > bv) { bv = v; best = k; }
        }
        earr[t] = (unsigned char)best;
        elem[n0 + t] = (unsigned char)best;
    }
    __syncthreads();
    if (t < 128 && 2 * t < nrow) {
        unsigned char lo = earr[2 * t];
        unsigned char hi = (2 * t + 1 < nrow) ? earr[2 * t + 1] : 0;
        packed[(n0 >> 1) + t] = (unsigned char)(lo | (hi << 4));
    }
}

__device__ __forceinline__ float zbl_edge_value_p(float xv, float A, float B,
                                                  float C) {
    float roa = xv * B;
    float phi = 0.1818f  * __expf(-3.2f    * roa)
              + 0.5099f  * __expf(-0.9423f * roa)
              + 0.2802f  * __expf(-0.4028f * roa)
              + 0.02817f * __expf(-0.2016f * roa);
    float v = A / xv * phi;
    float rr = xv / C;
    float rr2 = rr * rr;
    float rr3 = rr2 * rr;
    float rr6 = rr3 * rr3;
    float rr7 = rr6 * rr;
    float rr8 = rr7 * rr;
    float env = 1.0f - 28.0f * rr6 + 48.0f * rr7 - 21.0f * rr8;
    env = (xv < C) ? env : 0.0f;
    return 0.5f * v * env;
}

#define LOADBURST(c, RV, SV, XV)                                          \
    do {                                                                  \
        int _e0 = (c) * CHUNK;                                            \
        const int4*   _rp = (const int4*)(recv + _e0);                    \
        const int4*   _sp = (const int4*)(send + _e0);                    \
        const float4* _xp = (const float4*)(x + _e0);                     \
        int4 _ra = _rp[2 * t], _rb = _rp[2 * t + 1];                      \
        int4 _sa = _sp[2 * t], _sb = _sp[2 * t + 1];                      \
        float4 _xa = _xp[2 * t], _xb = _xp[2 * t + 1];                    \
        RV[0]=_ra.x; RV[1]=_ra.y; RV[2]=_ra.z; RV[3]=_ra.w;               \
        RV[4]=_rb.x; RV[5]=_rb.y; RV[6]=_rb.z; RV[7]=_rb.w;               \
        SV[0]=_sa.x; SV[1]=_sa.y; SV[2]=_sa.z; SV[3]=_sa.w;               \
        SV[4]=_sb.x; SV[5]=_sb.y; SV[6]=_sb.z; SV[7]=_sb.w;               \
        XV[0]=_xa.x; XV[1]=_xa.y; XV[2]=_xa.z; XV[3]=_xa.w;               \
        XV[4]=_xb.x; XV[5]=_xb.y; XV[6]=_xb.z; XV[7]=_xb.w;               \
    } while (0)

#define SCAN_W0()                                                         \
    do {                                                                  \
        if (t < 64) {                                                     \
            int a = (t < nb)      ? ((cntA[t]      + (PAD-1)) & ~(PAD-1)) : 0; \
            int b = (t + 64 < nb) ? ((cntA[t + 64] + (PAD-1)) & ~(PAD-1)) : 0; \
            int a0 = a, b0 = b;                                           \
            _Pragma("unroll")                                             \
            for (int d = 1; d < 64; d <<= 1) {                            \
                int va = __shfl_up(a, d);                                 \
                int vb = __shfl_up(b, d);                                 \
                if (t >= d) { a += va; b += vb; }                         \
            }                                                             \
            int totA = __shfl(a, 63);                                     \
            b += totA;                                                    \
            lds_off[t + 1]  = a;                                          \
            lds_off[t + 65] = b;                                          \
            curB[t]       = a - a0;                                       \
            curB[t + 64]  = b - b0;                                       \
            cntA[t] = 0; cntA[t + 64] = 0;                                \
            if (t == 0) lds_off[0] = 0;                                   \
        }                                                                 \
    } while (0)

// ---------------- Fused persistent: per-edge ZBL value + counting sort into
// fixed per-chunk slabs. pk map LDS-resident, loaded once per block; steady
// loop is 3 barriers/chunk with prefetch + writeout/count overlap.
__global__ __launch_bounds__(BS)
void zbl_fused(const float* __restrict__ x,
               const int* __restrict__ ei,
               const unsigned char* __restrict__ packed,
               const float4* __restrict__ etab_g,
               int n_edges, int n_nodes, int nb, int slab, int nchunks,
               float* __restrict__ valg,
               unsigned short* __restrict__ lrg,
               int* __restrict__ offg /*[c*(nb+1)+b]*/) {
    __shared__ unsigned char  pk[PKCAP];
    __shared__ float          val_s[SLABCAP];
    __shared__ unsigned short lr_s[SLABCAP];
    __shared__ int   lds_off[MAXBL + 1];
    __shared__ int   curB[MAXBL];
    __shared__ int   cntA[MAXBL];
    __shared__ float ptabA[NELEMS * NELEMS];
    __shared__ float ptabB[NELEMS * NELEMS];
    __shared__ float ptabC[NELEMS * NELEMS];

    int t = threadIdx.x;
    const int* send = ei;
    const int* recv = ei + n_edges;

    int c = blockIdx.x;
    if (c >= nchunks) return;

    // ---- one-time init: pk copy + ptab + staging zero + cntA zero
    {
        const unsigned int* ps = (const unsigned int*)packed;
        unsigned int* pd = (unsigned int*)pk;
        int npk = (n_nodes + 1) >> 1;
        int nw = npk >> 2;
        for (int i = t; i < nw; i += BS) pd[i] = ps[i];
        for (int i = (nw << 2) + t; i < npk; i += BS) pk[i] = packed[i];
    }
    for (int i = t; i < (SLABCAP >> 2); i += BS) {
        ((float4*)val_s)[i] = make_float4(0.f, 0.f, 0.f, 0.f);
        ((uint2*)lr_s)[i]   = make_uint2(0u, 0u);
    }
    if (t < MAXBL) cntA[t] = 0;
    if (t < NELEMS * NELEMS) {
        float4 u = etab_g[t / NELEMS];
        float4 v = etab_g[t % NELEMS];
        ptabA[t] = 14.3996f * u.x * v.x;
        ptabB[t] = (u.y + v.y) * INV_A_PREF;
        ptabC[t] = u.z + v.z;
    }

    // ---- prologue: load + count + scan for first chunk
    int rv[EPT], sv[EPT];
    float xv[EPT];
    bool full = (c * CHUNK + CHUNK <= n_edges);
    if (full) LOADBURST(c, rv, sv, xv);
    __syncthreads();   // init + loads in flight

    if (full) {
#pragma unroll
        for (int i = 0; i < EPT; ++i) atomicAdd(&cntA[rv[i] >> W_SHIFT], 1);
    } else {
        for (int e = c * CHUNK + t; e < n_edges; e += BS)
            atomicAdd(&cntA[recv[e] >> W_SHIFT], 1);
    }
    __syncthreads();   // counts ready
    SCAN_W0();
    __syncthreads();   // offsets + cursors ready

    // ---- steady loop: 3 barriers per chunk
    while (true) {
        int n = c + gridDim.x;
        bool has_next = (n < nchunks);
        bool nfull = has_next && (n * CHUNK + CHUNK <= n_edges);
        int rv2[EPT], sv2[EPT];
        float xv2[EPT];
        if (nfull) LOADBURST(n, rv2, sv2, xv2);   // prefetch: in flight below

        // place current chunk (exp math + LDS scatter)
        if (full) {
#pragma unroll
            for (int i = 0; i < EPT; ++i) {
                int s = sv[i], r = rv[i];
                int es = (pk[s >> 1] >> ((s & 1) << 2)) & 15;
                int er = (pk[r >> 1] >> ((r & 1) << 2)) & 15;
                int pi = es * NELEMS + er;
                float v = zbl_edge_value_p(xv[i], ptabA[pi], ptabB[pi], ptabC[pi]);
                int pos = atomicAdd(&curB[r >> W_SHIFT], 1);
                val_s[pos] = v;
                lr_s[pos] = (unsigned short)(r & (W - 1));
            }
        } else {
            for (int e = c * CHUNK + t; e < n_edges; e += BS) {
                int s = send[e], r = recv[e];
                int es = (pk[s >> 1] >> ((s & 1) << 2)) & 15;
                int er = (pk[r >> 1] >> ((r & 1) << 2)) & 15;
                int pi = es * NELEMS + er;
                float v = zbl_edge_value_p(x[e], ptabA[pi], ptabB[pi], ptabC[pi]);
                int pos = atomicAdd(&curB[r >> W_SHIFT], 1);
                val_s[pos] = v;
                lr_s[pos] = (unsigned short)(r & (W - 1));
            }
        }
        __syncthreads();   // B: staging complete

        // writeout current  ||  count next
        {
            int total = lds_off[nb];       // multiple of PAD
            size_t gb = (size_t)c * slab;
            float4* vdst = (float4*)(valg + gb);
            uint2*  ldst = (uint2*)(lrg + gb);
            int nt4 = total >> 2;
            for (int i = t; i < nt4; i += BS) {
                vdst[i] = ((float4*)val_s)[i];
                ldst[i] = ((uint2*)lr_s)[i];
            }
            if (t <= nb) offg[c * (nb + 1) + t] = lds_off[t];
        }
        if (has_next) {
            if (nfull) {
#pragma unroll
                for (int i = 0; i < EPT; ++i)
                    atomicAdd(&cntA[rv2[i] >> W_SHIFT], 1);
            } else {
                for (int e = n * CHUNK + t; e < n_edges; e += BS)
                    atomicAdd(&cntA[recv[e] >> W_SHIFT], 1);
            }
        }
        __syncthreads();   // B: writeout done, next counts ready

        if (!has_next) break;

        // zero staging (waves 1-7)  ||  scan next (wave 0)
        if (t >= 64) {
            for (int i = t - 64; i < (SLABCAP >> 2); i += BS - 64) {
                ((float4*)val_s)[i] = make_float4(0.f, 0.f, 0.f, 0.f);
                ((uint2*)lr_s)[i]   = make_uint2(0u, 0u);
            }
        } else {
            SCAN_W0();
        }
        __syncthreads();   // B: staging zeroed, offsets + cursors ready

        c = n;
        full = nfull;
#pragma unroll
        for (int i = 0; i < EPT; ++i) {
            rv[i] = rv2[i]; sv[i] = sv2[i]; xv[i] = xv2[i];
        }
    }
}

// ---------------- Pass 3: per-(bucket, slab-slice) segment reduction.
// 16-lane sub-waves each own a slab; float4/ushort4 loads (4 entries/lane).
__global__ __launch_bounds__(BS)
void zbl_reduce_seg(const float* __restrict__ valg,
                    const unsigned short* __restrict__ lrg,
                    const int* __restrict__ offg,
                    int nblk, int nb, int kred, int slab,
                    float* __restrict__ partial) {
    __shared__ float acc[W];
    int b = blockIdx.x;
    int j = blockIdx.y;
    int t = threadIdx.x;
    acc[t] = 0.0f;
    acc[t + BS] = 0.0f;
    __syncthreads();

    int stride = (nblk + kred - 1) / kred;
    int blk0 = j * stride;
    int blk1 = min(nblk, blk0 + stride);
    int wave = t >> 6, lane = t & 63;
    int sw = lane >> 4, li = lane & 15;           // 4 sub-waves of 16 lanes
    const int NSW = (BS / 64) * 4;                // 32 concurrent sub-waves

    for (int blk = blk0 + wave * 4 + sw; blk < blk1; blk += NSW) {
        const int* po = offg + (size_t)blk * (nb + 1) + b;
        int s0 = po[0], s1 = po[1];               // multiples of 4
        size_t gb = (size_t)blk * slab;
        const float4*  v4 = (const float4*)(valg + gb);
        const ushort4* l4 = (const ushort4*)(lrg + gb);
        for (int q = (s0 >> 2) + li; q < (s1 >> 2); q += 16) {
            float4  v = v4[q];
            ushort4 l = l4[q];
            atomicAdd(&acc[l.x], v.x);
            atomicAdd(&acc[l.y], v.y);
            atomicAdd(&acc[l.z], v.z);
            atomicAdd(&acc[l.w], v.w);
        }
    }
    __syncthreads();
    float* dst = partial + (((size_t)b * kred + j) << W_SHIFT);
    dst[t] = acc[t];
    dst[t + BS] = acc[t + BS];
}

// ---------------- Pass 4: sum kred partials per node -> out (float4)
__global__ void zbl_combine(const float* __restrict__ partial, int kred,
                            int n_nodes, float* __restrict__ out) {
    int q = blockIdx.x * blockDim.x + threadIdx.x;   // float4 index
    int n = q << 2;
    if (n >= n_nodes) return;
    int b = n >> W_SHIFT;
    int t = n & (W - 1);
    float4 s = make_float4(0.f, 0.f, 0.f, 0.f);
    for (int j = 0; j < kred; ++j) {
        const float4* p =
            (const float4*)(partial + (((size_t)b * kred + j) << W_SHIFT) + t);
        float4 v = *p;
        s.x += v.x; s.y += v.y; s.z += v.z; s.w += v.w;
    }
    if (n + 3 < n_nodes) {
        *(float4*)(out + n) = s;
    } else {
        out[n] = s.x;
        if (n + 1 < n_nodes) out[n + 1] = s.y;
        if (n + 2 < n_nodes) out[n + 2] = s.z;
    }
}

// ---------------- Fallback: direct global-atomic path
__global__ void zbl_edge_atomic(const float* __restrict__ x,
                                const int* __restrict__ edge_index,
                                const unsigned char* __restrict__ elem,
                                const float4* __restrict__ etab_g,
                                float* __restrict__ out, int n_edges) {
    int e = blockIdx.x * blockDim.x + threadIdx.x;
    if (e >= n_edges) return;
    int s = edge_index[e];
    int r = edge_index[n_edges + e];
    float4 u = etab_g[elem[s]];
    float4 w = etab_g[elem[r]];
    float v = zbl_edge_value_p(x[e], 14.3996f * u.x * w.x,
                               (u.y + w.y) * INV_A_PREF, u.z + w.z);
#if defined(__HIP_PLATFORM_AMD__)
    unsafeAtomicAdd(out + r, v);
#else
    atomicAdd(out + r, v);
#endif
}

extern "C" void kernel_launch(void* const* d_in, const int* in_sizes, int n_in,
                              void* d_out, int out_size, void* d_ws, size_t ws_size,
                              hipStream_t stream) {
    const float* x              = (const float*)d_in[0];
    const float* node_attrs     = (const float*)d_in[1];
    const int*   edge_index     = (const int*)d_in[2];
    const int*   atomic_numbers = (const int*)d_in[3];
    float*       out            = (float*)d_out;

    int n_edges = in_sizes[0];            // x is [E,1]
    int n_nodes = in_sizes[1] / NELEMS;   // node_attrs is [N,10]
    int nb = (n_nodes + W - 1) / W;       // buckets of 1024 nodes
    int nblk = (n_edges + CHUNK - 1) / CHUNK;
    int slab = (CHUNK + nb * (PAD - 1) + 3) & ~3;

    char* ws = (char*)d_ws;

    // workspace layout; pick largest kred that fits
    int kred = 0;
    size_t elem_o = 0, pk_o = 0, etab_o = 0,
           val_o = 0, lr_o = 0, offg_o = 0, part_o = 0;
    for (int try_k = 8; try_k >= 1; try_k >>= 1) {
        size_t off = 0;
        auto alloc = [&](size_t bytes) {
            size_t o = off;
            off = (off + bytes + 255) & ~(size_t)255;
            return o;
        };
        elem_o = alloc((size_t)n_nodes);
        pk_o   = alloc((size_t)(n_nodes + 1) / 2);
        etab_o = alloc(NELEMS * sizeof(float4));
        val_o  = alloc((size_t)nblk * slab * sizeof(float));
        lr_o   = alloc((size_t)nblk * slab * sizeof(unsigned short));
        offg_o = alloc((size_t)nblk * (nb + 1) * sizeof(int));
        part_o = alloc((size_t)nb * try_k * W * sizeof(float));
        if (off <= ws_size) { kred = try_k; break; }
    }

    unsigned char* elem   = (unsigned char*)(ws + elem_o);
    unsigned char* packed = (unsigned char*)(ws + pk_o);
    float4* etab_g        = (float4*)(ws + etab_o);

    int nb_nodes = (n_nodes + 255) / 256;
    zbl_node_elem<<<nb_nodes, 256, 0, stream>>>(node_attrs, atomic_numbers,
                                                elem, packed, etab_g, n_nodes);

    bool fast_ok = (kred >= 1) && (nb <= MAXBL) && (slab <= SLABCAP) &&
                   (((n_nodes + 1) >> 1) <= PKCAP);

    if (fast_ok) {
        float* valg         = (float*)(ws + val_o);
        unsigned short* lrg = (unsigned short*)(ws + lr_o);
        int* offg           = (int*)(ws + offg_o);
        float* partial      = (float*)(ws + part_o);

        int gridP = nblk < GRIDP ? nblk : GRIDP;
        zbl_fused<<<gridP, BS, 0, stream>>>(x, edge_index, packed, etab_g,
                                            n_edges, n_nodes, nb, slab, nblk,
                                            valg, lrg, offg);
        zbl_reduce_seg<<<dim3(nb, kred), BS, 0, stream>>>(valg, lrg, offg, nblk,
                                                          nb, kred, slab, partial);
        int nq = (n_nodes + 3) >> 2;
        zbl_combine<<<(nq + 255) / 256, 256, 0, stream>>>(partial, kred,
                                                          n_nodes, out);
    } else {
        // fallback: direct global-atomic path
        hipMemsetAsync(d_out, 0, (size_t)out_size * sizeof(float), stream);
        int nb_edges = (n_edges + 255) / 256;
        zbl_edge_atomic<<<nb_edges, 256, 0, stream>>>(x, edge_index, elem, etab_g,
                                                      out, n_edges);
    }
}